// Round 11
// baseline (633.401 us; speedup 1.0000x reference)
//
#include <hip/hip_runtime.h>
#include <cmath>

#define T_SEQ 2048
#define C_DIM 1024
#define BM 128
#define BN 128
#define BK 32

typedef unsigned short u16;
typedef unsigned int u32;
typedef short bf16x8 __attribute__((ext_vector_type(8)));
typedef _Float16 f16x8 __attribute__((ext_vector_type(8)));
typedef float f32x4 __attribute__((ext_vector_type(4)));
typedef unsigned short u16x8 __attribute__((ext_vector_type(8)));

#define AS1 __attribute__((address_space(1)))
#define AS3 __attribute__((address_space(3)))

__device__ __forceinline__ u16 f2bf(float f) {
    u32 u = __builtin_bit_cast(u32, f);
    u32 r = u + 0x7fffu + ((u >> 16) & 1u);
    return (u16)(r >> 16);
}
__device__ __forceinline__ u16 f2h(float f) {
    return __builtin_bit_cast(u16, (_Float16)f);
}
__device__ __forceinline__ float h2f(u16 h) {
    return (float)__builtin_bit_cast(_Float16, h);
}
__device__ __forceinline__ void gl_lds16(const void* g, void* l) {
    __builtin_amdgcn_global_load_lds((const AS1 u32*)g, (AS3 u32*)l, 16, 0, 0);
}

// XCD-aware bijective block swizzle (T1): all our grids have nwg % 8 == 0.
__device__ __forceinline__ int xcd_swz(int lin, int nwg) {
    return (lin & 7) * (nwg >> 3) + (lin >> 3);
}

// ---------------------------------------------------------------------------
// MFMA GEMM (used for GEMM1): C = A @ B^T, A 16-bit via global_load_lds.
// EPI: 0 = C f32 = acc   2 = C u16 = fp16(acc)
// DT:  0 = bf16  1 = fp16
// ---------------------------------------------------------------------------
template<int EPI, int DT>
__global__ __launch_bounds__(256)
void mfma_gemm(const u16* __restrict__ Ap, const u16* __restrict__ B0,
               void* __restrict__ Cout, int M, int N, int K)
{
    __shared__ u16 lds[2 * 2 * 4096];   // 2 buffers x (A, B) x 8KB
    const int tid  = threadIdx.x;
    const int lane = tid & 63;
    const int wid  = tid >> 6;
    const int wr = wid >> 1, wc = wid & 1;
    const int gx = gridDim.x;
    const int lin = xcd_swz(blockIdx.x + gx * blockIdx.y, gx * gridDim.y);
    const int m0 = (lin / gx) * BM;
    const int n0 = (lin % gx) * BN;
    const int NT = K / BK;

    f32x4 acc[4][4] = {};

    auto stage = [&](int it, int buf) {
        const int k0 = it * BK;
        u16* base = &lds[buf * 8192];
        #pragma unroll
        for (int i = 0; i < 2; ++i) {
            const int chunk = wid + 4 * i;
            const int rloc  = chunk * 16 + (lane >> 2);
            const int slot  = (lane & 3) ^ ((rloc >> 1) & 3);
            gl_lds16(B0 + (size_t)(n0 + rloc) * K + k0 + slot * 8,
                     base + 4096 + chunk * 512);
            gl_lds16(Ap + (size_t)(m0 + rloc) * K + k0 + slot * 8,
                     base + chunk * 512);
        }
    };

    auto compute = [&](int buf) {
        const u16* base = &lds[buf * 8192];
        if constexpr (DT == 0) {
            bf16x8 a[4], b[4];
            #pragma unroll
            for (int f = 0; f < 4; ++f) {
                const int row = wr * 64 + f * 16 + (lane & 15);
                const int sp  = ((lane >> 4) & 3) ^ ((row >> 1) & 3);
                a[f] = *(const bf16x8*)&base[row * 32 + sp * 8];
                const int rowb = wc * 64 + f * 16 + (lane & 15);
                const int spb  = ((lane >> 4) & 3) ^ ((rowb >> 1) & 3);
                b[f] = *(const bf16x8*)&base[4096 + rowb * 32 + spb * 8];
            }
            #pragma unroll
            for (int fm = 0; fm < 4; ++fm)
                #pragma unroll
                for (int fn = 0; fn < 4; ++fn)
                    acc[fm][fn] = __builtin_amdgcn_mfma_f32_16x16x32_bf16(a[fm], b[fn], acc[fm][fn], 0, 0, 0);
        } else {
            f16x8 a[4], b[4];
            #pragma unroll
            for (int f = 0; f < 4; ++f) {
                const int row = wr * 64 + f * 16 + (lane & 15);
                const int sp  = ((lane >> 4) & 3) ^ ((row >> 1) & 3);
                a[f] = *(const f16x8*)&base[row * 32 + sp * 8];
                const int rowb = wc * 64 + f * 16 + (lane & 15);
                const int spb  = ((lane >> 4) & 3) ^ ((rowb >> 1) & 3);
                b[f] = *(const f16x8*)&base[4096 + rowb * 32 + spb * 8];
            }
            #pragma unroll
            for (int fm = 0; fm < 4; ++fm)
                #pragma unroll
                for (int fn = 0; fn < 4; ++fn)
                    acc[fm][fn] = __builtin_amdgcn_mfma_f32_16x16x32_f16(a[fm], b[fn], acc[fm][fn], 0, 0, 0);
        }
    };

    stage(0, 0);
    int cur = 0;
    for (int it = 0; it < NT; ++it) {
        __syncthreads();
        if (it + 1 < NT) stage(it + 1, cur ^ 1);
        compute(cur);
        cur ^= 1;
    }

    const int crow0 = m0 + wr * 64 + ((lane >> 4) << 2);
    const int ccol  = n0 + wc * 64 + (lane & 15);
    #pragma unroll
    for (int fm = 0; fm < 4; ++fm)
        #pragma unroll
        for (int fn = 0; fn < 4; ++fn)
            #pragma unroll
            for (int r = 0; r < 4; ++r) {
                const size_t idx = (size_t)(crow0 + fm * 16 + r) * N + ccol + fn * 16;
                if constexpr (EPI == 0) ((float*)Cout)[idx] = acc[fm][fn][r];
                else                    ((u16*)Cout)[idx] = f2h(acc[fm][fn][r]);
            }
}

// ---------------------------------------------------------------------------
// Dual GEMM + product epilogue:
//   out = (A1 @ B1^T) * (A2 @ B2^T)   elementwise, f32 out
// ---------------------------------------------------------------------------
__global__ __launch_bounds__(256)
void dual_gemm(const u16* __restrict__ A1, const u16* __restrict__ B1, int K1,
               const u16* __restrict__ A2, const u16* __restrict__ B2, int K2,
               float* __restrict__ out, int M, int N)
{
    __shared__ u16 lds[2 * 2 * 4096];
    const int tid  = threadIdx.x;
    const int lane = tid & 63;
    const int wid  = tid >> 6;
    const int wr = wid >> 1, wc = wid & 1;
    const int gx = gridDim.x;
    const int lin = xcd_swz(blockIdx.x + gx * blockIdx.y, gx * gridDim.y);
    const int m0 = (lin / gx) * BM;
    const int n0 = (lin % gx) * BN;

    f32x4 acc1[4][4] = {};
    f32x4 acc2[4][4] = {};

    auto stage = [&](const u16* Ap, const u16* Bp, int K, int it, int buf) {
        const int k0 = it * BK;
        u16* base = &lds[buf * 8192];
        #pragma unroll
        for (int i = 0; i < 2; ++i) {
            const int chunk = wid + 4 * i;
            const int rloc  = chunk * 16 + (lane >> 2);
            const int slot  = (lane & 3) ^ ((rloc >> 1) & 3);
            gl_lds16(Bp + (size_t)(n0 + rloc) * K + k0 + slot * 8,
                     base + 4096 + chunk * 512);
            gl_lds16(Ap + (size_t)(m0 + rloc) * K + k0 + slot * 8,
                     base + chunk * 512);
        }
    };

    auto compute = [&](int buf, f32x4 (&acc)[4][4]) {
        const u16* base = &lds[buf * 8192];
        bf16x8 a[4], b[4];
        #pragma unroll
        for (int f = 0; f < 4; ++f) {
            const int row = wr * 64 + f * 16 + (lane & 15);
            const int sp  = ((lane >> 4) & 3) ^ ((row >> 1) & 3);
            a[f] = *(const bf16x8*)&base[row * 32 + sp * 8];
            const int rowb = wc * 64 + f * 16 + (lane & 15);
            const int spb  = ((lane >> 4) & 3) ^ ((rowb >> 1) & 3);
            b[f] = *(const bf16x8*)&base[4096 + rowb * 32 + spb * 8];
        }
        #pragma unroll
        for (int fm = 0; fm < 4; ++fm)
            #pragma unroll
            for (int fn = 0; fn < 4; ++fn)
                acc[fm][fn] = __builtin_amdgcn_mfma_f32_16x16x32_bf16(a[fm], b[fn], acc[fm][fn], 0, 0, 0);
    };

    const int NT1 = K1 / BK, NT2 = K2 / BK;
    stage(A1, B1, K1, 0, 0);
    int cur = 0;
    for (int it = 0; it < NT1; ++it) {
        __syncthreads();
        if (it + 1 < NT1) stage(A1, B1, K1, it + 1, cur ^ 1);
        else              stage(A2, B2, K2, 0, cur ^ 1);   // cross-phase prefetch
        compute(cur, acc1);
        cur ^= 1;
    }
    for (int it = 0; it < NT2; ++it) {
        __syncthreads();
        if (it + 1 < NT2) stage(A2, B2, K2, it + 1, cur ^ 1);
        compute(cur, acc2);
        cur ^= 1;
    }

    const int crow0 = m0 + wr * 64 + ((lane >> 4) << 2);
    const int ccol  = n0 + wc * 64 + (lane & 15);
    #pragma unroll
    for (int fm = 0; fm < 4; ++fm)
        #pragma unroll
        for (int fn = 0; fn < 4; ++fn)
            #pragma unroll
            for (int r = 0; r < 4; ++r) {
                const size_t idx = (size_t)(crow0 + fm * 16 + r) * N + ccol + fn * 16;
                out[idx] = acc1[fm][fn][r] * acc2[fm][fn][r];
            }
}

// ---------------------------------------------------------------------------
// Fused causal-conv + gate:  H = bf16( tanh(conv(y,Wf)) * sigmoid(conv(y,Wg)) )
// ---------------------------------------------------------------------------
__global__ __launch_bounds__(256)
void conv_gate(const u16* __restrict__ A, const u16* __restrict__ Wfgt,
               u16* __restrict__ H, int M)
{
    constexpr int KIT = C_DIM / BK;   // 32
    constexpr int NT  = 2 * KIT;      // 64
    __shared__ u16 lds[2 * 3 * 4096]; // 2 buf x (A, BF, BG)
    const int tid  = threadIdx.x;
    const int lane = tid & 63;
    const int wid  = tid >> 6;
    const int wr = wid >> 1, wc = wid & 1;
    const int gx = gridDim.x;
    const int lin = xcd_swz(blockIdx.x + gx * blockIdx.y, gx * gridDim.y);
    const int m0 = (lin / gx) * BM;
    const int n0 = (lin % gx) * BN;

    f32x4 accF[4][4] = {};
    f32x4 accG[4][4] = {};

    auto stage = [&](int it, int buf) {
        const int p  = it / KIT;                 // tap
        const int k0 = (it - p * KIT) * BK;
        u16* base = &lds[buf * 12288];
        const u16* BF = Wfgt + (size_t)p * 2 * C_DIM * C_DIM;
        const u16* BG = BF + (size_t)C_DIM * C_DIM;
        const int sh = (p == 0) ? 1 : 0;
        #pragma unroll
        for (int i = 0; i < 2; ++i) {
            const int chunk = wid + 4 * i;
            const int rloc  = chunk * 16 + (lane >> 2);
            const int slot  = (lane & 3) ^ ((rloc >> 1) & 3);
            int grow = m0 + rloc - sh;
            if (grow < 0) grow = 0;
            gl_lds16(A + (size_t)grow * C_DIM + k0 + slot * 8,
                     base + chunk * 512);
            gl_lds16(BF + (size_t)(n0 + rloc) * C_DIM + k0 + slot * 8,
                     base + 4096 + chunk * 512);
            gl_lds16(BG + (size_t)(n0 + rloc) * C_DIM + k0 + slot * 8,
                     base + 8192 + chunk * 512);
        }
    };

    auto compute = [&](int buf) {
        const u16* base = &lds[buf * 12288];
        bf16x8 a[4], bf[4], bg[4];
        #pragma unroll
        for (int f = 0; f < 4; ++f) {
            const int row = wr * 64 + f * 16 + (lane & 15);
            const int sp  = ((lane >> 4) & 3) ^ ((row >> 1) & 3);
            a[f] = *(const bf16x8*)&base[row * 32 + sp * 8];
            const int rowb = wc * 64 + f * 16 + (lane & 15);
            const int spb  = ((lane >> 4) & 3) ^ ((rowb >> 1) & 3);
            bf[f] = *(const bf16x8*)&base[4096 + rowb * 32 + spb * 8];
            bg[f] = *(const bf16x8*)&base[8192 + rowb * 32 + spb * 8];
        }
        #pragma unroll
        for (int fm = 0; fm < 4; ++fm)
            #pragma unroll
            for (int fn = 0; fn < 4; ++fn) {
                accF[fm][fn] = __builtin_amdgcn_mfma_f32_16x16x32_bf16(a[fm], bf[fn], accF[fm][fn], 0, 0, 0);
                accG[fm][fn] = __builtin_amdgcn_mfma_f32_16x16x32_bf16(a[fm], bg[fn], accG[fm][fn], 0, 0, 0);
            }
    };

    stage(0, 0);
    int cur = 0;
    for (int it = 0; it < NT; ++it) {
        __syncthreads();
        // zero the t==0 row of the A tile for the shifted tap
        if ((it / KIT) == 0 && (m0 % T_SEQ) == 0) {
            if (tid < 4) {
                u16x8 z = {0,0,0,0,0,0,0,0};
                *(u16x8*)&lds[cur * 12288 + tid * 8] = z;
            }
            __syncthreads();
        }
        if (it + 1 < NT) stage(it + 1, cur ^ 1);
        compute(cur);
        cur ^= 1;
    }

    const int crow0 = m0 + wr * 64 + ((lane >> 4) << 2);
    const int ccol  = n0 + wc * 64 + (lane & 15);
    #pragma unroll
    for (int fm = 0; fm < 4; ++fm)
        #pragma unroll
        for (int fn = 0; fn < 4; ++fn)
            #pragma unroll
            for (int r = 0; r < 4; ++r) {
                const float fv = accF[fm][fn][r];
                const float gv = accG[fm][fn][r];
                const float th = 1.0f - 2.0f / (expf(2.0f * fv) + 1.0f);
                const float sg = 1.0f / (1.0f + expf(-gv));
                H[(size_t)(crow0 + fm * 16 + r) * C_DIM + ccol + fn * 16] = f2bf(th * sg);
            }
}

// ---------------------------------------------------------------------------
// Segmented parallel scan, REGISTER-PACKED (raw fp16 pairs held as u32 regs):
//   P1: load kq ONCE into raw[64] + segment max -> LDS max-scan
//   P2: unpack from regs, seeded products; yb = bf16(xh * m) in-place -> scan
//   P3: unpack from regs, recompute chain, scale by prefix, write kv ONCE
// kq traffic 1r+1w (was 3r+1w). raw[] = 64 VGPRs; total ~94 < 128 cap @16 waves.
// Block: 32 channels x 32 segments (1024 thr); grid 8*32 = 256 blocks.
// ---------------------------------------------------------------------------
#define SSEG 32
#define SCHB 32
#define SSL (T_SEQ / SSEG)   // 64

__global__ __launch_bounds__(1024, 1)
void scan_kernel(u16* __restrict__ kq, u16* __restrict__ xyb)
{
    __shared__ float  lmax[SSEG][SCHB];
    __shared__ float2 lprod[SSEG][SCHB];
    const int blk = blockIdx.x;
    const int b   = blk >> 5;
    const int c0  = (blk & 31) * SCHB;
    const int ch  = threadIdx.x & (SCHB - 1);
    const int seg = threadIdx.x >> 5;
    const int c   = c0 + ch;
    const int t0  = seg * SSL;
    const size_t baseh = (size_t)b * T_SEQ * 2048 + 2 * c + (size_t)t0 * 2048;
    const size_t base1 = (size_t)b * T_SEQ * C_DIM + c + (size_t)t0 * C_DIM;

    u32 raw[SSL];

    // P1: single kq read into registers; segment max of squared magnitude
    float m2 = 0.f;
    {
        size_t idx = baseh;
        #pragma unroll
        for (int t = 0; t < SSL; ++t) {
            raw[t] = *(const u32*)&kq[idx];
            const float re = h2f((u16)(raw[t] & 0xffffu));
            const float im = h2f((u16)(raw[t] >> 16));
            m2 = fmaxf(m2, re * re + im * im);
            idx += 2048;
        }
    }
    lmax[seg][ch] = sqrtf(m2);
    __syncthreads();
    #pragma unroll
    for (int s = 1; s < SSEG; s <<= 1) {
        const float v = lmax[seg][ch];
        const float u = (seg >= s) ? lmax[seg - s][ch] : 0.f;
        __syncthreads();
        lmax[seg][ch] = fmaxf(v, u);
        __syncthreads();
    }
    const float premax = (seg > 0) ? lmax[seg - 1][ch] : 0.f;

    // P2: seeded products from registers; yb = bf16(xh * m) in-place
    float pr = 1.f, pi = 0.f;
    float m = premax;
    {
        size_t idx1 = base1;
        #pragma unroll
        for (int t = 0; t < SSL; ++t) {
            const float re = h2f((u16)(raw[t] & 0xffffu));
            const float im = h2f((u16)(raw[t] >> 16));
            m = fmaxf(m, sqrtf(re * re + im * im));
            const float inv = 1.f / m;
            const float r0 = re * inv, r1 = im * inv;
            const float nr = pr * r0 - pi * r1;
            const float ni = pr * r1 + pi * r0;
            pr = nr; pi = ni;
            const float xv = h2f(xyb[idx1]);
            xyb[idx1] = f2bf(xv * m);
            idx1 += C_DIM;
        }
    }
    lprod[seg][ch] = make_float2(pr, pi);
    __syncthreads();
    #pragma unroll
    for (int s = 1; s < SSEG; s <<= 1) {
        const float2 v = lprod[seg][ch];
        const float2 u = (seg >= s) ? lprod[seg - s][ch] : make_float2(1.f, 0.f);
        __syncthreads();
        lprod[seg][ch] = make_float2(u.x * v.x - u.y * v.y,
                                     u.x * v.y + u.y * v.x);
        __syncthreads();
    }
    float ppr = 1.f, ppi = 0.f;
    if (seg > 0) { const float2 pp = lprod[seg - 1][ch]; ppr = pp.x; ppi = pp.y; }

    // P3: recompute from registers, scale by prefix, single kq write
    pr = 1.f; pi = 0.f;
    m = premax;
    {
        size_t idx = baseh;
        #pragma unroll
        for (int t = 0; t < SSL; ++t) {
            const float re = h2f((u16)(raw[t] & 0xffffu));
            const float im = h2f((u16)(raw[t] >> 16));
            m = fmaxf(m, sqrtf(re * re + im * im));
            const float inv = 1.f / m;
            const float r0 = re * inv, r1 = im * inv;
            const float nr = pr * r0 - pi * r1;
            const float ni = pr * r1 + pi * r0;
            pr = nr; pi = ni;
            const float fr = ppr * nr - ppi * ni;
            const float fi = ppr * ni + ppi * nr;
            *(u32*)&kq[idx] = ((u32)f2bf(fi) << 16) | (u32)f2bf(fr);
            idx += 2048;
        }
    }
}

// ---------------------------------------------------------------------------
// Prep kernels
// ---------------------------------------------------------------------------
// Wk -> fp16, Wa -> bf16, Wo -> bf16 in one launch (ranges by flat index).
__global__ void cvt_weights(const float* __restrict__ Wk, const float* __restrict__ Wa,
                            const float* __restrict__ Wo, u16* __restrict__ Wkh,
                            u16* __restrict__ Wab, u16* __restrict__ Wob)
{
    const int n1 = 2048 * 1024, n2 = 2 * 2048 * 1024, n3 = n2 + 1024 * 1024;
    const int i = (blockIdx.x * blockDim.x + threadIdx.x) * 4;
    if (i < n1) {
        const float4 v = *(const float4*)&Wk[i];
        ushort4 o; o.x = f2h(v.x); o.y = f2h(v.y); o.z = f2h(v.z); o.w = f2h(v.w);
        *(ushort4*)&Wkh[i] = o;
    } else if (i < n2) {
        const int j = i - n1;
        const float4 v = *(const float4*)&Wa[j];
        ushort4 o; o.x = f2bf(v.x); o.y = f2bf(v.y); o.z = f2bf(v.z); o.w = f2bf(v.w);
        *(ushort4*)&Wab[j] = o;
    } else if (i < n3) {
        const int j = i - n2;
        const float4 v = *(const float4*)&Wo[j];
        ushort4 o; o.x = f2bf(v.x); o.y = f2bf(v.y); o.z = f2bf(v.z); o.w = f2bf(v.w);
        *(ushort4*)&Wob[j] = o;
    }
}

__global__ void cvt_f16(const float* __restrict__ src, u16* __restrict__ dst, int n)
{
    const int i = (blockIdx.x * blockDim.x + threadIdx.x) * 4;
    if (i >= n) return;
    const float4 v = *(const float4*)&src[i];
    ushort4 o;
    o.x = f2h(v.x); o.y = f2h(v.y); o.z = f2h(v.z); o.w = f2h(v.w);
    *(ushort4*)&dst[i] = o;
}

// Wf/Wg [2,K,N] (tap,k,n) -> Wfgt [tap][F/G][n][k] bf16
__global__ __launch_bounds__(256)
void wtrans(const float* __restrict__ Wf, const float* __restrict__ Wg,
            u16* __restrict__ dst)
{
    __shared__ float tile[64][65];
    const int z = blockIdx.z;
    const float* src = ((z < 2) ? Wf : Wg) + (size_t)(z & 1) * C_DIM * C_DIM;
    u16* d = dst + (size_t)(z & 1) * (2 * C_DIM) * C_DIM
                 + ((z < 2) ? (size_t)0 : (size_t)C_DIM * C_DIM);
    const int k0 = blockIdx.x * 64;
    const int n0 = blockIdx.y * 64;
    const int tx = threadIdx.x & 63, ty = threadIdx.x >> 6;
    #pragma unroll
    for (int i = 0; i < 16; ++i) {
        const int r = ty + i * 4;
        tile[r][tx] = src[(size_t)(k0 + r) * C_DIM + n0 + tx];
    }
    __syncthreads();
    #pragma unroll
    for (int i = 0; i < 16; ++i) {
        const int r = ty + i * 4;
        d[(size_t)(n0 + r) * C_DIM + k0 + tx] = f2bf(tile[tx][r]);
    }
}

// ---------------------------------------------------------------------------
// ws layout (bytes):
//   0         : kq  u16 [16384,2048]  67.1MB  (kh fp16 -> kv bf16 in-place)
//   67108864  : yb  u16 [16384,1024]  33.6MB  (xh fp16 -> yb bf16 in-place)
//   100663296 : hb  u16 [16384,1024]  33.6MB
//   134217728 : Wkh(f16) 4.2 | Wab 4.2 | Wfgt 8.4 | Wob 2.1   (~153MB total)
// ---------------------------------------------------------------------------
extern "C" void kernel_launch(void* const* d_in, const int* in_sizes, int n_in,
                              void* d_out, int out_size, void* d_ws, size_t ws_size,
                              hipStream_t stream)
{
    const float* x  = (const float*)d_in[0];
    const float* Wk = (const float*)d_in[1];
    const float* Wa = (const float*)d_in[2];
    const float* Wf = (const float*)d_in[3];
    const float* Wg = (const float*)d_in[4];
    const float* Wo = (const float*)d_in[5];
    float* out = (float*)d_out;

    const int M = 8 * T_SEQ;
    u16* kq   = (u16*)d_ws;
    u16* yb   = (u16*)((char*)d_ws + 67108864ull);   // xh first, then yb
    u16* hb   = (u16*)((char*)d_ws + 100663296ull);
    u16* Wkh  = (u16*)((char*)d_ws + 134217728ull);
    u16* Wab  = Wkh + 2048 * 1024;
    u16* Wfgt = Wab + 2048 * 1024;
    u16* Wob  = Wfgt + 2ull * 2048 * 1024;

    cvt_weights<<<(5 * 1024 * 1024 * 5 / 5 / 4 + 255) / 256 + 0, 256, 0, stream>>>(
        Wk, Wa, Wo, Wkh, Wab, Wob);   // covers 5M elements / 4 per thread
    wtrans  <<<dim3(16, 16, 4), 256, 0, stream>>>(Wf, Wg, Wfgt);
    cvt_f16 <<<(M * 1024 / 4) / 256, 256, 0, stream>>>(x, yb, M * 1024);  // xh

    // 1) kq = fp16( x @ Wk^T )  (fp16 MFMA, fp16 output)
    mfma_gemm<2, 1><<<dim3(2048 / BN, M / BM), 256, 0, stream>>>(
        yb, Wkh, kq, M, 2048, 1024);

    // 2) register-packed scan: kv bf16 in-place; yb = bf16(xh*scale) in-place
    scan_kernel<<<256, 1024, 0, stream>>>(kq, yb);

    // 3) hb = bf16(tanh(conv(yb,Wf)) * sigmoid(conv(yb,Wg)))
    conv_gate<<<dim3(1024 / BN, M / BM), 256, 0, stream>>>(yb, Wfgt, hb, M);

    // 4) out = (kv @ Wa^T) * (hb @ Wo^T)   (dual GEMM, product epilogue)
    dual_gemm<<<dim3(1024 / BN, M / BM), 256, 0, stream>>>(
        kq, Wab, 2048, hb, Wob, 1024, out, M, 1024);
}

// Round 12
// 463.830 us; speedup vs baseline: 1.3656x; 1.3656x over previous
//
#include <hip/hip_runtime.h>
#include <cmath>

#define T_SEQ 2048
#define C_DIM 1024
#define BM 128
#define BN 128
#define BK 32

typedef unsigned short u16;
typedef unsigned int u32;
typedef short bf16x8 __attribute__((ext_vector_type(8)));
typedef _Float16 f16x8 __attribute__((ext_vector_type(8)));
typedef float f32x4 __attribute__((ext_vector_type(4)));
typedef unsigned short u16x8 __attribute__((ext_vector_type(8)));

#define AS1 __attribute__((address_space(1)))
#define AS3 __attribute__((address_space(3)))

__device__ __forceinline__ u16 f2bf(float f) {
    u32 u = __builtin_bit_cast(u32, f);
    u32 r = u + 0x7fffu + ((u >> 16) & 1u);
    return (u16)(r >> 16);
}
__device__ __forceinline__ u16 f2h(float f) {
    return __builtin_bit_cast(u16, (_Float16)f);
}
__device__ __forceinline__ float h2f(u16 h) {
    return (float)__builtin_bit_cast(_Float16, h);
}
__device__ __forceinline__ void gl_lds16(const void* g, void* l) {
    __builtin_amdgcn_global_load_lds((const AS1 u32*)g, (AS3 u32*)l, 16, 0, 0);
}

// XCD-aware bijective block swizzle (T1): all our grids have nwg % 8 == 0.
__device__ __forceinline__ int xcd_swz(int lin, int nwg) {
    return (lin & 7) * (nwg >> 3) + (lin >> 3);
}

// ---------------------------------------------------------------------------
// MFMA GEMM (used for GEMM1): C = A @ B^T, A 16-bit via global_load_lds.
// EPI: 0 = C f32 = acc   2 = C u16 = fp16(acc)
// DT:  0 = bf16  1 = fp16
// ---------------------------------------------------------------------------
template<int EPI, int DT>
__global__ __launch_bounds__(256)
void mfma_gemm(const u16* __restrict__ Ap, const u16* __restrict__ B0,
               void* __restrict__ Cout, int M, int N, int K)
{
    __shared__ u16 lds[2 * 2 * 4096];   // 2 buffers x (A, B) x 8KB
    const int tid  = threadIdx.x;
    const int lane = tid & 63;
    const int wid  = tid >> 6;
    const int wr = wid >> 1, wc = wid & 1;
    const int gx = gridDim.x;
    const int lin = xcd_swz(blockIdx.x + gx * blockIdx.y, gx * gridDim.y);
    const int m0 = (lin / gx) * BM;
    const int n0 = (lin % gx) * BN;
    const int NT = K / BK;

    f32x4 acc[4][4] = {};

    auto stage = [&](int it, int buf) {
        const int k0 = it * BK;
        u16* base = &lds[buf * 8192];
        #pragma unroll
        for (int i = 0; i < 2; ++i) {
            const int chunk = wid + 4 * i;
            const int rloc  = chunk * 16 + (lane >> 2);
            const int slot  = (lane & 3) ^ ((rloc >> 1) & 3);
            gl_lds16(B0 + (size_t)(n0 + rloc) * K + k0 + slot * 8,
                     base + 4096 + chunk * 512);
            gl_lds16(Ap + (size_t)(m0 + rloc) * K + k0 + slot * 8,
                     base + chunk * 512);
        }
    };

    auto compute = [&](int buf) {
        const u16* base = &lds[buf * 8192];
        if constexpr (DT == 0) {
            bf16x8 a[4], b[4];
            #pragma unroll
            for (int f = 0; f < 4; ++f) {
                const int row = wr * 64 + f * 16 + (lane & 15);
                const int sp  = ((lane >> 4) & 3) ^ ((row >> 1) & 3);
                a[f] = *(const bf16x8*)&base[row * 32 + sp * 8];
                const int rowb = wc * 64 + f * 16 + (lane & 15);
                const int spb  = ((lane >> 4) & 3) ^ ((rowb >> 1) & 3);
                b[f] = *(const bf16x8*)&base[4096 + rowb * 32 + spb * 8];
            }
            #pragma unroll
            for (int fm = 0; fm < 4; ++fm)
                #pragma unroll
                for (int fn = 0; fn < 4; ++fn)
                    acc[fm][fn] = __builtin_amdgcn_mfma_f32_16x16x32_bf16(a[fm], b[fn], acc[fm][fn], 0, 0, 0);
        } else {
            f16x8 a[4], b[4];
            #pragma unroll
            for (int f = 0; f < 4; ++f) {
                const int row = wr * 64 + f * 16 + (lane & 15);
                const int sp  = ((lane >> 4) & 3) ^ ((row >> 1) & 3);
                a[f] = *(const f16x8*)&base[row * 32 + sp * 8];
                const int rowb = wc * 64 + f * 16 + (lane & 15);
                const int spb  = ((lane >> 4) & 3) ^ ((rowb >> 1) & 3);
                b[f] = *(const f16x8*)&base[4096 + rowb * 32 + spb * 8];
            }
            #pragma unroll
            for (int fm = 0; fm < 4; ++fm)
                #pragma unroll
                for (int fn = 0; fn < 4; ++fn)
                    acc[fm][fn] = __builtin_amdgcn_mfma_f32_16x16x32_f16(a[fm], b[fn], acc[fm][fn], 0, 0, 0);
        }
    };

    stage(0, 0);
    int cur = 0;
    for (int it = 0; it < NT; ++it) {
        __syncthreads();
        if (it + 1 < NT) stage(it + 1, cur ^ 1);
        compute(cur);
        cur ^= 1;
    }

    const int crow0 = m0 + wr * 64 + ((lane >> 4) << 2);
    const int ccol  = n0 + wc * 64 + (lane & 15);
    #pragma unroll
    for (int fm = 0; fm < 4; ++fm)
        #pragma unroll
        for (int fn = 0; fn < 4; ++fn)
            #pragma unroll
            for (int r = 0; r < 4; ++r) {
                const size_t idx = (size_t)(crow0 + fm * 16 + r) * N + ccol + fn * 16;
                if constexpr (EPI == 0) ((float*)Cout)[idx] = acc[fm][fn][r];
                else                    ((u16*)Cout)[idx] = f2h(acc[fm][fn][r]);
            }
}

// ---------------------------------------------------------------------------
// Dual GEMM + product epilogue:
//   out = (A1 @ B1^T) * (A2 @ B2^T)   elementwise, f32 out
// ---------------------------------------------------------------------------
__global__ __launch_bounds__(256)
void dual_gemm(const u16* __restrict__ A1, const u16* __restrict__ B1, int K1,
               const u16* __restrict__ A2, const u16* __restrict__ B2, int K2,
               float* __restrict__ out, int M, int N)
{
    __shared__ u16 lds[2 * 2 * 4096];
    const int tid  = threadIdx.x;
    const int lane = tid & 63;
    const int wid  = tid >> 6;
    const int wr = wid >> 1, wc = wid & 1;
    const int gx = gridDim.x;
    const int lin = xcd_swz(blockIdx.x + gx * blockIdx.y, gx * gridDim.y);
    const int m0 = (lin / gx) * BM;
    const int n0 = (lin % gx) * BN;

    f32x4 acc1[4][4] = {};
    f32x4 acc2[4][4] = {};

    auto stage = [&](const u16* Ap, const u16* Bp, int K, int it, int buf) {
        const int k0 = it * BK;
        u16* base = &lds[buf * 8192];
        #pragma unroll
        for (int i = 0; i < 2; ++i) {
            const int chunk = wid + 4 * i;
            const int rloc  = chunk * 16 + (lane >> 2);
            const int slot  = (lane & 3) ^ ((rloc >> 1) & 3);
            gl_lds16(Bp + (size_t)(n0 + rloc) * K + k0 + slot * 8,
                     base + 4096 + chunk * 512);
            gl_lds16(Ap + (size_t)(m0 + rloc) * K + k0 + slot * 8,
                     base + chunk * 512);
        }
    };

    auto compute = [&](int buf, f32x4 (&acc)[4][4]) {
        const u16* base = &lds[buf * 8192];
        bf16x8 a[4], b[4];
        #pragma unroll
        for (int f = 0; f < 4; ++f) {
            const int row = wr * 64 + f * 16 + (lane & 15);
            const int sp  = ((lane >> 4) & 3) ^ ((row >> 1) & 3);
            a[f] = *(const bf16x8*)&base[row * 32 + sp * 8];
            const int rowb = wc * 64 + f * 16 + (lane & 15);
            const int spb  = ((lane >> 4) & 3) ^ ((rowb >> 1) & 3);
            b[f] = *(const bf16x8*)&base[4096 + rowb * 32 + spb * 8];
        }
        #pragma unroll
        for (int fm = 0; fm < 4; ++fm)
            #pragma unroll
            for (int fn = 0; fn < 4; ++fn)
                acc[fm][fn] = __builtin_amdgcn_mfma_f32_16x16x32_bf16(a[fm], b[fn], acc[fm][fn], 0, 0, 0);
    };

    const int NT1 = K1 / BK, NT2 = K2 / BK;
    stage(A1, B1, K1, 0, 0);
    int cur = 0;
    for (int it = 0; it < NT1; ++it) {
        __syncthreads();
        if (it + 1 < NT1) stage(A1, B1, K1, it + 1, cur ^ 1);
        else              stage(A2, B2, K2, 0, cur ^ 1);   // cross-phase prefetch
        compute(cur, acc1);
        cur ^= 1;
    }
    for (int it = 0; it < NT2; ++it) {
        __syncthreads();
        if (it + 1 < NT2) stage(A2, B2, K2, it + 1, cur ^ 1);
        compute(cur, acc2);
        cur ^= 1;
    }

    const int crow0 = m0 + wr * 64 + ((lane >> 4) << 2);
    const int ccol  = n0 + wc * 64 + (lane & 15);
    #pragma unroll
    for (int fm = 0; fm < 4; ++fm)
        #pragma unroll
        for (int fn = 0; fn < 4; ++fn)
            #pragma unroll
            for (int r = 0; r < 4; ++r) {
                const size_t idx = (size_t)(crow0 + fm * 16 + r) * N + ccol + fn * 16;
                out[idx] = acc1[fm][fn][r] * acc2[fm][fn][r];
            }
}

// ---------------------------------------------------------------------------
// Fused causal-conv + gate:  H = bf16( tanh(conv(y,Wf)) * sigmoid(conv(y,Wg)) )
// ---------------------------------------------------------------------------
__global__ __launch_bounds__(256)
void conv_gate(const u16* __restrict__ A, const u16* __restrict__ Wfgt,
               u16* __restrict__ H, int M)
{
    constexpr int KIT = C_DIM / BK;   // 32
    constexpr int NT  = 2 * KIT;      // 64
    __shared__ u16 lds[2 * 3 * 4096]; // 2 buf x (A, BF, BG)
    const int tid  = threadIdx.x;
    const int lane = tid & 63;
    const int wid  = tid >> 6;
    const int wr = wid >> 1, wc = wid & 1;
    const int gx = gridDim.x;
    const int lin = xcd_swz(blockIdx.x + gx * blockIdx.y, gx * gridDim.y);
    const int m0 = (lin / gx) * BM;
    const int n0 = (lin % gx) * BN;

    f32x4 accF[4][4] = {};
    f32x4 accG[4][4] = {};

    auto stage = [&](int it, int buf) {
        const int p  = it / KIT;                 // tap
        const int k0 = (it - p * KIT) * BK;
        u16* base = &lds[buf * 12288];
        const u16* BF = Wfgt + (size_t)p * 2 * C_DIM * C_DIM;
        const u16* BG = BF + (size_t)C_DIM * C_DIM;
        const int sh = (p == 0) ? 1 : 0;
        #pragma unroll
        for (int i = 0; i < 2; ++i) {
            const int chunk = wid + 4 * i;
            const int rloc  = chunk * 16 + (lane >> 2);
            const int slot  = (lane & 3) ^ ((rloc >> 1) & 3);
            int grow = m0 + rloc - sh;
            if (grow < 0) grow = 0;
            gl_lds16(A + (size_t)grow * C_DIM + k0 + slot * 8,
                     base + chunk * 512);
            gl_lds16(BF + (size_t)(n0 + rloc) * C_DIM + k0 + slot * 8,
                     base + 4096 + chunk * 512);
            gl_lds16(BG + (size_t)(n0 + rloc) * C_DIM + k0 + slot * 8,
                     base + 8192 + chunk * 512);
        }
    };

    auto compute = [&](int buf) {
        const u16* base = &lds[buf * 12288];
        bf16x8 a[4], bf[4], bg[4];
        #pragma unroll
        for (int f = 0; f < 4; ++f) {
            const int row = wr * 64 + f * 16 + (lane & 15);
            const int sp  = ((lane >> 4) & 3) ^ ((row >> 1) & 3);
            a[f] = *(const bf16x8*)&base[row * 32 + sp * 8];
            const int rowb = wc * 64 + f * 16 + (lane & 15);
            const int spb  = ((lane >> 4) & 3) ^ ((rowb >> 1) & 3);
            bf[f] = *(const bf16x8*)&base[4096 + rowb * 32 + spb * 8];
            bg[f] = *(const bf16x8*)&base[8192 + rowb * 32 + spb * 8];
        }
        #pragma unroll
        for (int fm = 0; fm < 4; ++fm)
            #pragma unroll
            for (int fn = 0; fn < 4; ++fn) {
                accF[fm][fn] = __builtin_amdgcn_mfma_f32_16x16x32_bf16(a[fm], bf[fn], accF[fm][fn], 0, 0, 0);
                accG[fm][fn] = __builtin_amdgcn_mfma_f32_16x16x32_bf16(a[fm], bg[fn], accG[fm][fn], 0, 0, 0);
            }
    };

    stage(0, 0);
    int cur = 0;
    for (int it = 0; it < NT; ++it) {
        __syncthreads();
        // zero the t==0 row of the A tile for the shifted tap
        if ((it / KIT) == 0 && (m0 % T_SEQ) == 0) {
            if (tid < 4) {
                u16x8 z = {0,0,0,0,0,0,0,0};
                *(u16x8*)&lds[cur * 12288 + tid * 8] = z;
            }
            __syncthreads();
        }
        if (it + 1 < NT) stage(it + 1, cur ^ 1);
        compute(cur);
        cur ^= 1;
    }

    const int crow0 = m0 + wr * 64 + ((lane >> 4) << 2);
    const int ccol  = n0 + wc * 64 + (lane & 15);
    #pragma unroll
    for (int fm = 0; fm < 4; ++fm)
        #pragma unroll
        for (int fn = 0; fn < 4; ++fn)
            #pragma unroll
            for (int r = 0; r < 4; ++r) {
                const float fv = accF[fm][fn][r];
                const float gv = accG[fm][fn][r];
                const float th = 1.0f - 2.0f / (expf(2.0f * fv) + 1.0f);
                const float sg = 1.0f / (1.0f + expf(-gv));
                H[(size_t)(crow0 + fm * 16 + r) * C_DIM + ccol + fn * 16] = f2bf(th * sg);
            }
}

// ---------------------------------------------------------------------------
// Segmented parallel scan, 3-pass STREAMING (no register arrays -> no spill),
// 128B-coalesced kq access (32 channels x 4B per 32-lane group):
//   P1: stream kq, segment max -> LDS max-scan
//   P2: stream kq, seeded products; yb = bf16(h2f(xh) * m) in-place -> prod-scan
//   P3: stream kq, recompute, scale by prefix, write kv bf16 in-place
// Block: 32 channels x 32 segments (1024 thr); grid 8*32 = 256 blocks.
// ---------------------------------------------------------------------------
#define SSEG 32
#define SCHB 32
#define SSL (T_SEQ / SSEG)   // 64

__global__ __launch_bounds__(1024, 1)
void scan_kernel(u16* __restrict__ kq, u16* __restrict__ xyb)
{
    __shared__ float  lmax[SSEG][SCHB];
    __shared__ float2 lprod[SSEG][SCHB];
    const int blk = blockIdx.x;
    const int b   = blk >> 5;
    const int c0  = (blk & 31) * SCHB;
    const int ch  = threadIdx.x & (SCHB - 1);
    const int seg = threadIdx.x >> 5;
    const int c   = c0 + ch;
    const int t0  = seg * SSL;
    const size_t baseh = (size_t)b * T_SEQ * 2048 + 2 * c + (size_t)t0 * 2048;
    const size_t base1 = (size_t)b * T_SEQ * C_DIM + c + (size_t)t0 * C_DIM;

    // P1: streaming segment max (squared magnitudes; sqrt once)
    float m2 = 0.f;
    {
        size_t idx = baseh;
        for (int t = 0; t < SSL; ++t) {
            const u32 v = *(const u32*)&kq[idx];
            const float re = h2f((u16)(v & 0xffffu));
            const float im = h2f((u16)(v >> 16));
            m2 = fmaxf(m2, re * re + im * im);
            idx += 2048;
        }
    }
    lmax[seg][ch] = sqrtf(m2);
    __syncthreads();
    #pragma unroll
    for (int s = 1; s < SSEG; s <<= 1) {
        const float v = lmax[seg][ch];
        const float u = (seg >= s) ? lmax[seg - s][ch] : 0.f;
        __syncthreads();
        lmax[seg][ch] = fmaxf(v, u);
        __syncthreads();
    }
    const float premax = (seg > 0) ? lmax[seg - 1][ch] : 0.f;

    // P2: streaming seeded products; yb = bf16(xh * m) in-place
    float pr = 1.f, pi = 0.f;
    float m = premax;
    {
        size_t idx = baseh, idx1 = base1;
        for (int t = 0; t < SSL; ++t) {
            const u32 v = *(const u32*)&kq[idx];
            const float re = h2f((u16)(v & 0xffffu));
            const float im = h2f((u16)(v >> 16));
            m = fmaxf(m, sqrtf(re * re + im * im));
            const float inv = 1.f / m;
            const float r0 = re * inv, r1 = im * inv;
            const float nr = pr * r0 - pi * r1;
            const float ni = pr * r1 + pi * r0;
            pr = nr; pi = ni;
            const float xv = h2f(xyb[idx1]);
            xyb[idx1] = f2bf(xv * m);
            idx += 2048; idx1 += C_DIM;
        }
    }
    lprod[seg][ch] = make_float2(pr, pi);
    __syncthreads();
    #pragma unroll
    for (int s = 1; s < SSEG; s <<= 1) {
        const float2 v = lprod[seg][ch];
        const float2 u = (seg >= s) ? lprod[seg - s][ch] : make_float2(1.f, 0.f);
        __syncthreads();
        lprod[seg][ch] = make_float2(u.x * v.x - u.y * v.y,
                                     u.x * v.y + u.y * v.x);
        __syncthreads();
    }
    float ppr = 1.f, ppi = 0.f;
    if (seg > 0) { const float2 pp = lprod[seg - 1][ch]; ppr = pp.x; ppi = pp.y; }

    // P3: stream again, recompute, scale by prefix, write kv bf16 in-place
    pr = 1.f; pi = 0.f;
    m = premax;
    {
        size_t idx = baseh;
        for (int t = 0; t < SSL; ++t) {
            const u32 v = *(const u32*)&kq[idx];
            const float re = h2f((u16)(v & 0xffffu));
            const float im = h2f((u16)(v >> 16));
            m = fmaxf(m, sqrtf(re * re + im * im));
            const float inv = 1.f / m;
            const float r0 = re * inv, r1 = im * inv;
            const float nr = pr * r0 - pi * r1;
            const float ni = pr * r1 + pi * r0;
            pr = nr; pi = ni;
            const float fr = ppr * nr - ppi * ni;
            const float fi = ppr * ni + ppi * nr;
            *(u32*)&kq[idx] = ((u32)f2bf(fi) << 16) | (u32)f2bf(fr);
            idx += 2048;
        }
    }
}

// ---------------------------------------------------------------------------
// Prep kernels
// ---------------------------------------------------------------------------
// Wk -> fp16, Wa -> bf16, Wo -> bf16 in one launch (ranges by flat index).
__global__ void cvt_weights(const float* __restrict__ Wk, const float* __restrict__ Wa,
                            const float* __restrict__ Wo, u16* __restrict__ Wkh,
                            u16* __restrict__ Wab, u16* __restrict__ Wob)
{
    const int n1 = 2048 * 1024, n2 = 2 * 2048 * 1024, n3 = n2 + 1024 * 1024;
    const int i = (blockIdx.x * blockDim.x + threadIdx.x) * 4;
    if (i < n1) {
        const float4 v = *(const float4*)&Wk[i];
        ushort4 o; o.x = f2h(v.x); o.y = f2h(v.y); o.z = f2h(v.z); o.w = f2h(v.w);
        *(ushort4*)&Wkh[i] = o;
    } else if (i < n2) {
        const int j = i - n1;
        const float4 v = *(const float4*)&Wa[j];
        ushort4 o; o.x = f2bf(v.x); o.y = f2bf(v.y); o.z = f2bf(v.z); o.w = f2bf(v.w);
        *(ushort4*)&Wab[j] = o;
    } else if (i < n3) {
        const int j = i - n2;
        const float4 v = *(const float4*)&Wo[j];
        ushort4 o; o.x = f2bf(v.x); o.y = f2bf(v.y); o.z = f2bf(v.z); o.w = f2bf(v.w);
        *(ushort4*)&Wob[j] = o;
    }
}

__global__ void cvt_f16(const float* __restrict__ src, u16* __restrict__ dst, int n)
{
    const int i = (blockIdx.x * blockDim.x + threadIdx.x) * 4;
    if (i >= n) return;
    const float4 v = *(const float4*)&src[i];
    ushort4 o;
    o.x = f2h(v.x); o.y = f2h(v.y); o.z = f2h(v.z); o.w = f2h(v.w);
    *(ushort4*)&dst[i] = o;
}

// Wf/Wg [2,K,N] (tap,k,n) -> Wfgt [tap][F/G][n][k] bf16
__global__ __launch_bounds__(256)
void wtrans(const float* __restrict__ Wf, const float* __restrict__ Wg,
            u16* __restrict__ dst)
{
    __shared__ float tile[64][65];
    const int z = blockIdx.z;
    const float* src = ((z < 2) ? Wf : Wg) + (size_t)(z & 1) * C_DIM * C_DIM;
    u16* d = dst + (size_t)(z & 1) * (2 * C_DIM) * C_DIM
                 + ((z < 2) ? (size_t)0 : (size_t)C_DIM * C_DIM);
    const int k0 = blockIdx.x * 64;
    const int n0 = blockIdx.y * 64;
    const int tx = threadIdx.x & 63, ty = threadIdx.x >> 6;
    #pragma unroll
    for (int i = 0; i < 16; ++i) {
        const int r = ty + i * 4;
        tile[r][tx] = src[(size_t)(k0 + r) * C_DIM + n0 + tx];
    }
    __syncthreads();
    #pragma unroll
    for (int i = 0; i < 16; ++i) {
        const int r = ty + i * 4;
        d[(size_t)(n0 + r) * C_DIM + k0 + tx] = f2bf(tile[tx][r]);
    }
}

// ---------------------------------------------------------------------------
// ws layout (bytes):
//   0         : kq  u16 [16384,2048]  67.1MB  (kh fp16 -> kv bf16 in-place)
//   67108864  : yb  u16 [16384,1024]  33.6MB  (xh fp16 -> yb bf16 in-place)
//   100663296 : hb  u16 [16384,1024]  33.6MB
//   134217728 : Wkh(f16) 4.2 | Wab 4.2 | Wfgt 8.4 | Wob 2.1   (~153MB total)
// ---------------------------------------------------------------------------
extern "C" void kernel_launch(void* const* d_in, const int* in_sizes, int n_in,
                              void* d_out, int out_size, void* d_ws, size_t ws_size,
                              hipStream_t stream)
{
    const float* x  = (const float*)d_in[0];
    const float* Wk = (const float*)d_in[1];
    const float* Wa = (const float*)d_in[2];
    const float* Wf = (const float*)d_in[3];
    const float* Wg = (const float*)d_in[4];
    const float* Wo = (const float*)d_in[5];
    float* out = (float*)d_out;

    const int M = 8 * T_SEQ;
    u16* kq   = (u16*)d_ws;
    u16* yb   = (u16*)((char*)d_ws + 67108864ull);   // xh first, then yb
    u16* hb   = (u16*)((char*)d_ws + 100663296ull);
    u16* Wkh  = (u16*)((char*)d_ws + 134217728ull);
    u16* Wab  = Wkh + 2048 * 1024;
    u16* Wfgt = Wab + 2048 * 1024;
    u16* Wob  = Wfgt + 2ull * 2048 * 1024;

    // 5M weight elements, 4 per thread
    cvt_weights<<<(5 * 1024 * 1024 / 4 + 255) / 256, 256, 0, stream>>>(
        Wk, Wa, Wo, Wkh, Wab, Wob);
    wtrans  <<<dim3(16, 16, 4), 256, 0, stream>>>(Wf, Wg, Wfgt);
    cvt_f16 <<<(M * 1024 / 4) / 256, 256, 0, stream>>>(x, yb, M * 1024);  // xh

    // 1) kq = fp16( x @ Wk^T )  (fp16 MFMA, fp16 output)
    mfma_gemm<2, 1><<<dim3(2048 / BN, M / BM), 256, 0, stream>>>(
        yb, Wkh, kq, M, 2048, 1024);

    // 2) streaming scan: kv bf16 in-place; yb = bf16(xh*scale) in-place
    scan_kernel<<<256, 1024, 0, stream>>>(kq, yb);

    // 3) hb = bf16(tanh(conv(yb,Wf)) * sigmoid(conv(yb,Wg)))
    conv_gate<<<dim3(1024 / BN, M / BM), 256, 0, stream>>>(yb, Wfgt, hb, M);

    // 4) out = (kv @ Wa^T) * (hb @ Wo^T)   (dual GEMM, product epilogue)
    dual_gemm<<<dim3(1024 / BN, M / BM), 256, 0, stream>>>(
        kq, Wab, 2048, hb, Wob, 1024, out, M, 1024);
}

// Round 13
// 454.852 us; speedup vs baseline: 1.3925x; 1.0197x over previous
//
#include <hip/hip_runtime.h>
#include <cmath>

#define T_SEQ 2048
#define C_DIM 1024
#define BM 128
#define BN 128
#define BK 32

typedef unsigned short u16;
typedef unsigned int u32;
typedef short bf16x8 __attribute__((ext_vector_type(8)));
typedef _Float16 f16x8 __attribute__((ext_vector_type(8)));
typedef float f32x4 __attribute__((ext_vector_type(4)));
typedef unsigned short u16x8 __attribute__((ext_vector_type(8)));

#define AS1 __attribute__((address_space(1)))
#define AS3 __attribute__((address_space(3)))

__device__ __forceinline__ u16 f2bf(float f) {
    u32 u = __builtin_bit_cast(u32, f);
    u32 r = u + 0x7fffu + ((u >> 16) & 1u);
    return (u16)(r >> 16);
}
__device__ __forceinline__ u16 f2h(float f) {
    return __builtin_bit_cast(u16, (_Float16)f);
}
__device__ __forceinline__ float h2f(u16 h) {
    return (float)__builtin_bit_cast(_Float16, h);
}
__device__ __forceinline__ void gl_lds16(const void* g, void* l) {
    __builtin_amdgcn_global_load_lds((const AS1 u32*)g, (AS3 u32*)l, 16, 0, 0);
}

// XCD-aware bijective block swizzle (T1): all our grids have nwg % 8 == 0.
__device__ __forceinline__ int xcd_swz(int lin, int nwg) {
    return (lin & 7) * (nwg >> 3) + (lin >> 3);
}

#define SBAR() do { __builtin_amdgcn_sched_barrier(0); \
                    __builtin_amdgcn_s_barrier(); \
                    __builtin_amdgcn_sched_barrier(0); } while (0)
#define VMC(n) do { asm volatile("s_waitcnt vmcnt(" #n ")" ::: "memory"); \
                    __builtin_amdgcn_sched_barrier(0); } while (0)

// ---------------------------------------------------------------------------
// 8-phase 256x256 fp16 GEMM (T3+T4+T5):  C u16 = fp16( A @ B^T )
// A [M,K], B [N,K] fp16 row-major. BK=64 (2 kh-halves), 512 thr = 8 waves
// (2M x 4N), per-wave out 128x64, acc[8][4] f32x4. 4 phases/K-tile:
// (kh0,mq0)(kh0,mq1)(kh1,mq0)(kh1,mq1), 16 MFMA each. One 16KB half-unit
// staged per phase (order Akh0,Bkh0,Akh1,Bkh1 of tile t+1); every unit lands
// >=3 barrier-separated phases before first read. vmcnt(6) at P1/P3 only.
// LDS 128KB = 2 buf x (A 2x8K + B 2x8K u16).
// ---------------------------------------------------------------------------
__global__ __launch_bounds__(512, 2)
void gemm8(const u16* __restrict__ Ap, const u16* __restrict__ Bp,
           u16* __restrict__ Cout, int M, int N, int K)
{
    __shared__ u16 lds[2 * 32768];
    const int tid  = threadIdx.x;
    const int lane = tid & 63;
    const int wid  = tid >> 6;        // 0..7
    const int wrow = wid >> 2;        // 0..1
    const int wcol = wid & 3;         // 0..3
    const int gx = gridDim.x;
    const int lin = xcd_swz(blockIdx.x + gx * blockIdx.y, gx * gridDim.y);
    const int m0 = (lin / gx) * 256;
    const int n0 = (lin % gx) * 256;
    const int NT = K / 64;

    f32x4 acc[8][4] = {};

    // stage half-unit u of K-tile t:  u: 0=A/kh0  1=B/kh0  2=A/kh1  3=B/kh1
    auto stageu = [&](int t, int u) {
        const int isB = u & 1, kh = u >> 1;
        u16* ubase = &lds[(t & 1) * 32768 + isB * 16384 + kh * 8192];
        const u16* src = isB ? Bp + (size_t)n0 * K : Ap + (size_t)m0 * K;
        const int k0 = t * 64 + kh * 32;
        #pragma unroll
        for (int j = 0; j < 2; ++j) {
            const int c = wid + 8 * j;            // chunk 0..15 (1KB each)
            const int p = c * 64 + lane;          // linear 16B-chunk id 0..1023
            const int row = p >> 2;               // 0..255
            const int sp  = (p & 3) ^ ((row >> 1) & 3);
            gl_lds16(src + (size_t)row * K + k0 + sp * 8, ubase + c * 512);
        }
    };

    auto lda = [&](int buf, int kh, int mq, f16x8 (&a)[4]) {
        const u16* base = &lds[buf * 32768 + kh * 8192];
        #pragma unroll
        for (int f = 0; f < 4; ++f) {
            const int row = wrow * 128 + mq * 64 + f * 16 + (lane & 15);
            const int sp  = (lane >> 4) ^ ((row >> 1) & 3);
            a[f] = *(const f16x8*)&base[row * 32 + sp * 8];
        }
    };
    auto ldb = [&](int buf, int kh, f16x8 (&b)[4]) {
        const u16* base = &lds[buf * 32768 + 16384 + kh * 8192];
        #pragma unroll
        for (int f = 0; f < 4; ++f) {
            const int row = wcol * 64 + f * 16 + (lane & 15);
            const int sp  = (lane >> 4) ^ ((row >> 1) & 3);
            b[f] = *(const f16x8*)&base[row * 32 + sp * 8];
        }
    };
    auto mm = [&](const f16x8 (&a)[4], const f16x8 (&b)[4], int mq) {
        __builtin_amdgcn_s_setprio(1);
        #pragma unroll
        for (int fm = 0; fm < 4; ++fm)
            #pragma unroll
            for (int fn = 0; fn < 4; ++fn)
                acc[mq * 4 + fm][fn] = __builtin_amdgcn_mfma_f32_16x16x32_f16(
                    a[fm], b[fn], acc[mq * 4 + fm][fn], 0, 0, 0);
        __builtin_amdgcn_s_setprio(0);
    };

    // prologue: tile 0, all 4 half-units; drain kh0 units, barrier.
    stageu(0, 0); stageu(0, 1); stageu(0, 2); stageu(0, 3);
    VMC(4);
    SBAR();

    f16x8 a[4], b[4];
    for (int t = 0; t < NT; ++t) {
        const int buf = t & 1;
        const bool more = (t + 1 < NT);
        // P1: (kh0, mq0); stage (t+1, Akh0)
        if (more) { stageu(t + 1, 0); VMC(6); } else { VMC(4); }
        lda(buf, 0, 0, a); ldb(buf, 0, b);
        mm(a, b, 0);
        SBAR();
        // P2: (kh0, mq1); stage (t+1, Bkh0); B regs reused
        if (more) stageu(t + 1, 1);
        lda(buf, 0, 1, a);
        mm(a, b, 1);
        SBAR();
        // P3: (kh1, mq0); stage (t+1, Akh1)
        if (more) { stageu(t + 1, 2); VMC(6); } else { VMC(0); }
        lda(buf, 1, 0, a); ldb(buf, 1, b);
        mm(a, b, 0);
        SBAR();
        // P4: (kh1, mq1); stage (t+1, Bkh1); B regs reused
        if (more) stageu(t + 1, 3);
        lda(buf, 1, 1, a);
        mm(a, b, 1);
        SBAR();
    }

    const int crow0 = m0 + wrow * 128 + ((lane >> 4) << 2);
    const int ccol  = n0 + wcol * 64 + (lane & 15);
    #pragma unroll
    for (int mi = 0; mi < 8; ++mi)
        #pragma unroll
        for (int fn = 0; fn < 4; ++fn)
            #pragma unroll
            for (int r = 0; r < 4; ++r)
                Cout[(size_t)(crow0 + mi * 16 + r) * N + ccol + fn * 16] =
                    f2h(acc[mi][fn][r]);
}

// ---------------------------------------------------------------------------
// Dual GEMM + product epilogue:
//   out = (A1 @ B1^T) * (A2 @ B2^T)   elementwise, f32 out
// ---------------------------------------------------------------------------
__global__ __launch_bounds__(256)
void dual_gemm(const u16* __restrict__ A1, const u16* __restrict__ B1, int K1,
               const u16* __restrict__ A2, const u16* __restrict__ B2, int K2,
               float* __restrict__ out, int M, int N)
{
    __shared__ u16 lds[2 * 2 * 4096];
    const int tid  = threadIdx.x;
    const int lane = tid & 63;
    const int wid  = tid >> 6;
    const int wr = wid >> 1, wc = wid & 1;
    const int gx = gridDim.x;
    const int lin = xcd_swz(blockIdx.x + gx * blockIdx.y, gx * gridDim.y);
    const int m0 = (lin / gx) * BM;
    const int n0 = (lin % gx) * BN;

    f32x4 acc1[4][4] = {};
    f32x4 acc2[4][4] = {};

    auto stage = [&](const u16* Ap, const u16* Bp, int K, int it, int buf) {
        const int k0 = it * BK;
        u16* base = &lds[buf * 8192];
        #pragma unroll
        for (int i = 0; i < 2; ++i) {
            const int chunk = wid + 4 * i;
            const int rloc  = chunk * 16 + (lane >> 2);
            const int slot  = (lane & 3) ^ ((rloc >> 1) & 3);
            gl_lds16(Bp + (size_t)(n0 + rloc) * K + k0 + slot * 8,
                     base + 4096 + chunk * 512);
            gl_lds16(Ap + (size_t)(m0 + rloc) * K + k0 + slot * 8,
                     base + chunk * 512);
        }
    };

    auto compute = [&](int buf, f32x4 (&acc)[4][4]) {
        const u16* base = &lds[buf * 8192];
        bf16x8 a[4], b[4];
        #pragma unroll
        for (int f = 0; f < 4; ++f) {
            const int row = wr * 64 + f * 16 + (lane & 15);
            const int sp  = ((lane >> 4) & 3) ^ ((row >> 1) & 3);
            a[f] = *(const bf16x8*)&base[row * 32 + sp * 8];
            const int rowb = wc * 64 + f * 16 + (lane & 15);
            const int spb  = ((lane >> 4) & 3) ^ ((rowb >> 1) & 3);
            b[f] = *(const bf16x8*)&base[4096 + rowb * 32 + spb * 8];
        }
        #pragma unroll
        for (int fm = 0; fm < 4; ++fm)
            #pragma unroll
            for (int fn = 0; fn < 4; ++fn)
                acc[fm][fn] = __builtin_amdgcn_mfma_f32_16x16x32_bf16(a[fm], b[fn], acc[fm][fn], 0, 0, 0);
    };

    const int NT1 = K1 / BK, NT2 = K2 / BK;
    stage(A1, B1, K1, 0, 0);
    int cur = 0;
    for (int it = 0; it < NT1; ++it) {
        __syncthreads();
        if (it + 1 < NT1) stage(A1, B1, K1, it + 1, cur ^ 1);
        else              stage(A2, B2, K2, 0, cur ^ 1);   // cross-phase prefetch
        compute(cur, acc1);
        cur ^= 1;
    }
    for (int it = 0; it < NT2; ++it) {
        __syncthreads();
        if (it + 1 < NT2) stage(A2, B2, K2, it + 1, cur ^ 1);
        compute(cur, acc2);
        cur ^= 1;
    }

    const int crow0 = m0 + wr * 64 + ((lane >> 4) << 2);
    const int ccol  = n0 + wc * 64 + (lane & 15);
    #pragma unroll
    for (int fm = 0; fm < 4; ++fm)
        #pragma unroll
        for (int fn = 0; fn < 4; ++fn)
            #pragma unroll
            for (int r = 0; r < 4; ++r) {
                const size_t idx = (size_t)(crow0 + fm * 16 + r) * N + ccol + fn * 16;
                out[idx] = acc1[fm][fn][r] * acc2[fm][fn][r];
            }
}

// ---------------------------------------------------------------------------
// Fused causal-conv + gate:  H = bf16( tanh(conv(y,Wf)) * sigmoid(conv(y,Wg)) )
// ---------------------------------------------------------------------------
__global__ __launch_bounds__(256)
void conv_gate(const u16* __restrict__ A, const u16* __restrict__ Wfgt,
               u16* __restrict__ H, int M)
{
    constexpr int KIT = C_DIM / BK;   // 32
    constexpr int NT  = 2 * KIT;      // 64
    __shared__ u16 lds[2 * 3 * 4096]; // 2 buf x (A, BF, BG)
    const int tid  = threadIdx.x;
    const int lane = tid & 63;
    const int wid  = tid >> 6;
    const int wr = wid >> 1, wc = wid & 1;
    const int gx = gridDim.x;
    const int lin = xcd_swz(blockIdx.x + gx * blockIdx.y, gx * gridDim.y);
    const int m0 = (lin / gx) * BM;
    const int n0 = (lin % gx) * BN;

    f32x4 accF[4][4] = {};
    f32x4 accG[4][4] = {};

    auto stage = [&](int it, int buf) {
        const int p  = it / KIT;                 // tap
        const int k0 = (it - p * KIT) * BK;
        u16* base = &lds[buf * 12288];
        const u16* BF = Wfgt + (size_t)p * 2 * C_DIM * C_DIM;
        const u16* BG = BF + (size_t)C_DIM * C_DIM;
        const int sh = (p == 0) ? 1 : 0;
        #pragma unroll
        for (int i = 0; i < 2; ++i) {
            const int chunk = wid + 4 * i;
            const int rloc  = chunk * 16 + (lane >> 2);
            const int slot  = (lane & 3) ^ ((rloc >> 1) & 3);
            int grow = m0 + rloc - sh;
            if (grow < 0) grow = 0;
            gl_lds16(A + (size_t)grow * C_DIM + k0 + slot * 8,
                     base + chunk * 512);
            gl_lds16(BF + (size_t)(n0 + rloc) * C_DIM + k0 + slot * 8,
                     base + 4096 + chunk * 512);
            gl_lds16(BG + (size_t)(n0 + rloc) * C_DIM + k0 + slot * 8,
                     base + 8192 + chunk * 512);
        }
    };

    auto compute = [&](int buf) {
        const u16* base = &lds[buf * 12288];
        bf16x8 a[4], bf[4], bg[4];
        #pragma unroll
        for (int f = 0; f < 4; ++f) {
            const int row = wr * 64 + f * 16 + (lane & 15);
            const int sp  = ((lane >> 4) & 3) ^ ((row >> 1) & 3);
            a[f] = *(const bf16x8*)&base[row * 32 + sp * 8];
            const int rowb = wc * 64 + f * 16 + (lane & 15);
            const int spb  = ((lane >> 4) & 3) ^ ((rowb >> 1) & 3);
            bf[f] = *(const bf16x8*)&base[4096 + rowb * 32 + spb * 8];
            bg[f] = *(const bf16x8*)&base[8192 + rowb * 32 + spb * 8];
        }
        #pragma unroll
        for (int fm = 0; fm < 4; ++fm)
            #pragma unroll
            for (int fn = 0; fn < 4; ++fn) {
                accF[fm][fn] = __builtin_amdgcn_mfma_f32_16x16x32_bf16(a[fm], bf[fn], accF[fm][fn], 0, 0, 0);
                accG[fm][fn] = __builtin_amdgcn_mfma_f32_16x16x32_bf16(a[fm], bg[fn], accG[fm][fn], 0, 0, 0);
            }
    };

    stage(0, 0);
    int cur = 0;
    for (int it = 0; it < NT; ++it) {
        __syncthreads();
        // zero the t==0 row of the A tile for the shifted tap
        if ((it / KIT) == 0 && (m0 % T_SEQ) == 0) {
            if (tid < 4) {
                u16x8 z = {0,0,0,0,0,0,0,0};
                *(u16x8*)&lds[cur * 12288 + tid * 8] = z;
            }
            __syncthreads();
        }
        if (it + 1 < NT) stage(it + 1, cur ^ 1);
        compute(cur);
        cur ^= 1;
    }

    const int crow0 = m0 + wr * 64 + ((lane >> 4) << 2);
    const int ccol  = n0 + wc * 64 + (lane & 15);
    #pragma unroll
    for (int fm = 0; fm < 4; ++fm)
        #pragma unroll
        for (int fn = 0; fn < 4; ++fn)
            #pragma unroll
            for (int r = 0; r < 4; ++r) {
                const float fv = accF[fm][fn][r];
                const float gv = accG[fm][fn][r];
                const float th = 1.0f - 2.0f / (expf(2.0f * fv) + 1.0f);
                const float sg = 1.0f / (1.0f + expf(-gv));
                H[(size_t)(crow0 + fm * 16 + r) * C_DIM + ccol + fn * 16] = f2bf(th * sg);
            }
}

// ---------------------------------------------------------------------------
// Segmented parallel scan, 3-pass STREAMING (no register arrays -> no spill),
// 128B-coalesced kq access.
// ---------------------------------------------------------------------------
#define SSEG 32
#define SCHB 32
#define SSL (T_SEQ / SSEG)   // 64

__global__ __launch_bounds__(1024, 1)
void scan_kernel(u16* __restrict__ kq, u16* __restrict__ xyb)
{
    __shared__ float  lmax[SSEG][SCHB];
    __shared__ float2 lprod[SSEG][SCHB];
    const int blk = blockIdx.x;
    const int b   = blk >> 5;
    const int c0  = (blk & 31) * SCHB;
    const int ch  = threadIdx.x & (SCHB - 1);
    const int seg = threadIdx.x >> 5;
    const int c   = c0 + ch;
    const int t0  = seg * SSL;
    const size_t baseh = (size_t)b * T_SEQ * 2048 + 2 * c + (size_t)t0 * 2048;
    const size_t base1 = (size_t)b * T_SEQ * C_DIM + c + (size_t)t0 * C_DIM;

    float m2 = 0.f;
    {
        size_t idx = baseh;
        for (int t = 0; t < SSL; ++t) {
            const u32 v = *(const u32*)&kq[idx];
            const float re = h2f((u16)(v & 0xffffu));
            const float im = h2f((u16)(v >> 16));
            m2 = fmaxf(m2, re * re + im * im);
            idx += 2048;
        }
    }
    lmax[seg][ch] = sqrtf(m2);
    __syncthreads();
    #pragma unroll
    for (int s = 1; s < SSEG; s <<= 1) {
        const float v = lmax[seg][ch];
        const float u = (seg >= s) ? lmax[seg - s][ch] : 0.f;
        __syncthreads();
        lmax[seg][ch] = fmaxf(v, u);
        __syncthreads();
    }
    const float premax = (seg > 0) ? lmax[seg - 1][ch] : 0.f;

    float pr = 1.f, pi = 0.f;
    float m = premax;
    {
        size_t idx = baseh, idx1 = base1;
        for (int t = 0; t < SSL; ++t) {
            const u32 v = *(const u32*)&kq[idx];
            const float re = h2f((u16)(v & 0xffffu));
            const float im = h2f((u16)(v >> 16));
            m = fmaxf(m, sqrtf(re * re + im * im));
            const float inv = 1.f / m;
            const float r0 = re * inv, r1 = im * inv;
            const float nr = pr * r0 - pi * r1;
            const float ni = pr * r1 + pi * r0;
            pr = nr; pi = ni;
            const float xv = h2f(xyb[idx1]);
            xyb[idx1] = f2bf(xv * m);
            idx += 2048; idx1 += C_DIM;
        }
    }
    lprod[seg][ch] = make_float2(pr, pi);
    __syncthreads();
    #pragma unroll
    for (int s = 1; s < SSEG; s <<= 1) {
        const float2 v = lprod[seg][ch];
        const float2 u = (seg >= s) ? lprod[seg - s][ch] : make_float2(1.f, 0.f);
        __syncthreads();
        lprod[seg][ch] = make_float2(u.x * v.x - u.y * v.y,
                                     u.x * v.y + u.y * v.x);
        __syncthreads();
    }
    float ppr = 1.f, ppi = 0.f;
    if (seg > 0) { const float2 pp = lprod[seg - 1][ch]; ppr = pp.x; ppi = pp.y; }

    pr = 1.f; pi = 0.f;
    m = premax;
    {
        size_t idx = baseh;
        for (int t = 0; t < SSL; ++t) {
            const u32 v = *(const u32*)&kq[idx];
            const float re = h2f((u16)(v & 0xffffu));
            const float im = h2f((u16)(v >> 16));
            m = fmaxf(m, sqrtf(re * re + im * im));
            const float inv = 1.f / m;
            const float r0 = re * inv, r1 = im * inv;
            const float nr = pr * r0 - pi * r1;
            const float ni = pr * r1 + pi * r0;
            pr = nr; pi = ni;
            const float fr = ppr * nr - ppi * ni;
            const float fi = ppr * ni + ppi * nr;
            *(u32*)&kq[idx] = ((u32)f2bf(fi) << 16) | (u32)f2bf(fr);
            idx += 2048;
        }
    }
}

// ---------------------------------------------------------------------------
// Prep kernels
// ---------------------------------------------------------------------------
__global__ void cvt_weights(const float* __restrict__ Wk, const float* __restrict__ Wa,
                            const float* __restrict__ Wo, u16* __restrict__ Wkh,
                            u16* __restrict__ Wab, u16* __restrict__ Wob)
{
    const int n1 = 2048 * 1024, n2 = 2 * 2048 * 1024, n3 = n2 + 1024 * 1024;
    const int i = (blockIdx.x * blockDim.x + threadIdx.x) * 4;
    if (i < n1) {
        const float4 v = *(const float4*)&Wk[i];
        ushort4 o; o.x = f2h(v.x); o.y = f2h(v.y); o.z = f2h(v.z); o.w = f2h(v.w);
        *(ushort4*)&Wkh[i] = o;
    } else if (i < n2) {
        const int j = i - n1;
        const float4 v = *(const float4*)&Wa[j];
        ushort4 o; o.x = f2bf(v.x); o.y = f2bf(v.y); o.z = f2bf(v.z); o.w = f2bf(v.w);
        *(ushort4*)&Wab[j] = o;
    } else if (i < n3) {
        const int j = i - n2;
        const float4 v = *(const float4*)&Wo[j];
        ushort4 o; o.x = f2bf(v.x); o.y = f2bf(v.y); o.z = f2bf(v.z); o.w = f2bf(v.w);
        *(ushort4*)&Wob[j] = o;
    }
}

__global__ void cvt_f16(const float* __restrict__ src, u16* __restrict__ dst, int n)
{
    const int i = (blockIdx.x * blockDim.x + threadIdx.x) * 4;
    if (i >= n) return;
    const float4 v = *(const float4*)&src[i];
    ushort4 o;
    o.x = f2h(v.x); o.y = f2h(v.y); o.z = f2h(v.z); o.w = f2h(v.w);
    *(ushort4*)&dst[i] = o;
}

// Wf/Wg [2,K,N] (tap,k,n) -> Wfgt [tap][F/G][n][k] bf16
__global__ __launch_bounds__(256)
void wtrans(const float* __restrict__ Wf, const float* __restrict__ Wg,
            u16* __restrict__ dst)
{
    __shared__ float tile[64][65];
    const int z = blockIdx.z;
    const float* src = ((z < 2) ? Wf : Wg) + (size_t)(z & 1) * C_DIM * C_DIM;
    u16* d = dst + (size_t)(z & 1) * (2 * C_DIM) * C_DIM
                 + ((z < 2) ? (size_t)0 : (size_t)C_DIM * C_DIM);
    const int k0 = blockIdx.x * 64;
    const int n0 = blockIdx.y * 64;
    const int tx = threadIdx.x & 63, ty = threadIdx.x >> 6;
    #pragma unroll
    for (int i = 0; i < 16; ++i) {
        const int r = ty + i * 4;
        tile[r][tx] = src[(size_t)(k0 + r) * C_DIM + n0 + tx];
    }
    __syncthreads();
    #pragma unroll
    for (int i = 0; i < 16; ++i) {
        const int r = ty + i * 4;
        d[(size_t)(n0 + r) * C_DIM + k0 + tx] = f2bf(tile[tx][r]);
    }
}

// ---------------------------------------------------------------------------
// ws layout (bytes):
//   0         : kq  u16 [16384,2048]  67.1MB  (kh fp16 -> kv bf16 in-place)
//   67108864  : yb  u16 [16384,1024]  33.6MB  (xh fp16 -> yb bf16 in-place)
//   100663296 : hb  u16 [16384,1024]  33.6MB
//   134217728 : Wkh(f16) 4.2 | Wab 4.2 | Wfgt 8.4 | Wob 2.1   (~153MB total)
// ---------------------------------------------------------------------------
extern "C" void kernel_launch(void* const* d_in, const int* in_sizes, int n_in,
                              void* d_out, int out_size, void* d_ws, size_t ws_size,
                              hipStream_t stream)
{
    const float* x  = (const float*)d_in[0];
    const float* Wk = (const float*)d_in[1];
    const float* Wa = (const float*)d_in[2];
    const float* Wf = (const float*)d_in[3];
    const float* Wg = (const float*)d_in[4];
    const float* Wo = (const float*)d_in[5];
    float* out = (float*)d_out;

    const int M = 8 * T_SEQ;
    u16* kq   = (u16*)d_ws;
    u16* yb   = (u16*)((char*)d_ws + 67108864ull);   // xh first, then yb
    u16* hb   = (u16*)((char*)d_ws + 100663296ull);
    u16* Wkh  = (u16*)((char*)d_ws + 134217728ull);
    u16* Wab  = Wkh + 2048 * 1024;
    u16* Wfgt = Wab + 2048 * 1024;
    u16* Wob  = Wfgt + 2ull * 2048 * 1024;

    cvt_weights<<<(5 * 1024 * 1024 / 4 + 255) / 256, 256, 0, stream>>>(
        Wk, Wa, Wo, Wkh, Wab, Wob);
    wtrans  <<<dim3(16, 16, 4), 256, 0, stream>>>(Wf, Wg, Wfgt);
    cvt_f16 <<<(M * 1024 / 4) / 256, 256, 0, stream>>>(x, yb, M * 1024);  // xh

    // 1) kq = fp16( x @ Wk^T )  (8-phase 256^2 fp16 MFMA)
    gemm8<<<dim3(2048 / 256, M / 256), 512, 0, stream>>>(
        yb, Wkh, kq, M, 2048, 1024);

    // 2) streaming scan: kv bf16 in-place; yb = bf16(xh*scale) in-place
    scan_kernel<<<256, 1024, 0, stream>>>(kq, yb);

    // 3) hb = bf16(tanh(conv(yb,Wf)) * sigmoid(conv(yb,Wg)))
    conv_gate<<<dim3(1024 / BN, M / BM), 256, 0, stream>>>(yb, Wfgt, hb, M);

    // 4) out = (kv @ Wa^T) * (hb @ Wo^T)   (dual GEMM, product epilogue)
    dual_gemm<<<dim3(1024 / BN, M / BM), 256, 0, stream>>>(
        kq, Wab, 2048, hb, Wob, 1024, out, M, 1024);
}

// Round 14
// 450.260 us; speedup vs baseline: 1.4067x; 1.0102x over previous
//
#include <hip/hip_runtime.h>
#include <cmath>

#define T_SEQ 2048
#define C_DIM 1024
#define BM 128
#define BN 128
#define BK 32

typedef unsigned short u16;
typedef unsigned int u32;
typedef short bf16x8 __attribute__((ext_vector_type(8)));
typedef _Float16 f16x8 __attribute__((ext_vector_type(8)));
typedef float f32x4 __attribute__((ext_vector_type(4)));
typedef unsigned short u16x8 __attribute__((ext_vector_type(8)));

#define AS1 __attribute__((address_space(1)))
#define AS3 __attribute__((address_space(3)))

__device__ __forceinline__ u16 f2bf(float f) {
    u32 u = __builtin_bit_cast(u32, f);
    u32 r = u + 0x7fffu + ((u >> 16) & 1u);
    return (u16)(r >> 16);
}
__device__ __forceinline__ u16 f2h(float f) {
    return __builtin_bit_cast(u16, (_Float16)f);
}
__device__ __forceinline__ float h2f(u16 h) {
    return (float)__builtin_bit_cast(_Float16, h);
}
__device__ __forceinline__ void gl_lds16(const void* g, void* l) {
    __builtin_amdgcn_global_load_lds((const AS1 u32*)g, (AS3 u32*)l, 16, 0, 0);
}

// XCD-aware bijective block swizzle (T1): all our grids have nwg % 8 == 0.
__device__ __forceinline__ int xcd_swz(int lin, int nwg) {
    return (lin & 7) * (nwg >> 3) + (lin >> 3);
}

#define SBAR() do { __builtin_amdgcn_sched_barrier(0); \
                    __builtin_amdgcn_s_barrier(); \
                    __builtin_amdgcn_sched_barrier(0); } while (0)
#define VMC(n) do { asm volatile("s_waitcnt vmcnt(" #n ")" ::: "memory"); \
                    __builtin_amdgcn_sched_barrier(0); } while (0)

// ---------------------------------------------------------------------------
// 8-phase 256x256 fp16 GEMM (T3+T4+T5):  C u16 = fp16( A @ B^T )
// (validated R13)  BK=64, 512 thr = 8 waves (2Mx4N), per-wave out 128x64.
// 4 phases/K-tile, 16 MFMA each; one 16KB half-unit staged per phase;
// vmcnt(6) at P1/P3 only.  LDS 128KB.
// ---------------------------------------------------------------------------
__global__ __launch_bounds__(512, 2)
void gemm8(const u16* __restrict__ Ap, const u16* __restrict__ Bp,
           u16* __restrict__ Cout, int M, int N, int K)
{
    __shared__ u16 lds[2 * 32768];
    const int tid  = threadIdx.x;
    const int lane = tid & 63;
    const int wid  = tid >> 6;        // 0..7
    const int wrow = wid >> 2;        // 0..1
    const int wcol = wid & 3;         // 0..3
    const int gx = gridDim.x;
    const int lin = xcd_swz(blockIdx.x + gx * blockIdx.y, gx * gridDim.y);
    const int m0 = (lin / gx) * 256;
    const int n0 = (lin % gx) * 256;
    const int NT = K / 64;

    f32x4 acc[8][4] = {};

    auto stageu = [&](int t, int u) {
        const int isB = u & 1, kh = u >> 1;
        u16* ubase = &lds[(t & 1) * 32768 + isB * 16384 + kh * 8192];
        const u16* src = isB ? Bp + (size_t)n0 * K : Ap + (size_t)m0 * K;
        const int k0 = t * 64 + kh * 32;
        #pragma unroll
        for (int j = 0; j < 2; ++j) {
            const int c = wid + 8 * j;
            const int p = c * 64 + lane;
            const int row = p >> 2;
            const int sp  = (p & 3) ^ ((row >> 1) & 3);
            gl_lds16(src + (size_t)row * K + k0 + sp * 8, ubase + c * 512);
        }
    };

    auto lda = [&](int buf, int kh, int mq, f16x8 (&a)[4]) {
        const u16* base = &lds[buf * 32768 + kh * 8192];
        #pragma unroll
        for (int f = 0; f < 4; ++f) {
            const int row = wrow * 128 + mq * 64 + f * 16 + (lane & 15);
            const int sp  = (lane >> 4) ^ ((row >> 1) & 3);
            a[f] = *(const f16x8*)&base[row * 32 + sp * 8];
        }
    };
    auto ldb = [&](int buf, int kh, f16x8 (&b)[4]) {
        const u16* base = &lds[buf * 32768 + 16384 + kh * 8192];
        #pragma unroll
        for (int f = 0; f < 4; ++f) {
            const int row = wcol * 64 + f * 16 + (lane & 15);
            const int sp  = (lane >> 4) ^ ((row >> 1) & 3);
            b[f] = *(const f16x8*)&base[row * 32 + sp * 8];
        }
    };
    auto mm = [&](const f16x8 (&a)[4], const f16x8 (&b)[4], int mq) {
        __builtin_amdgcn_s_setprio(1);
        #pragma unroll
        for (int fm = 0; fm < 4; ++fm)
            #pragma unroll
            for (int fn = 0; fn < 4; ++fn)
                acc[mq * 4 + fm][fn] = __builtin_amdgcn_mfma_f32_16x16x32_f16(
                    a[fm], b[fn], acc[mq * 4 + fm][fn], 0, 0, 0);
        __builtin_amdgcn_s_setprio(0);
    };

    stageu(0, 0); stageu(0, 1); stageu(0, 2); stageu(0, 3);
    VMC(4);
    SBAR();

    f16x8 a[4], b[4];
    for (int t = 0; t < NT; ++t) {
        const int buf = t & 1;
        const bool more = (t + 1 < NT);
        if (more) { stageu(t + 1, 0); VMC(6); } else { VMC(4); }
        lda(buf, 0, 0, a); ldb(buf, 0, b);
        mm(a, b, 0);
        SBAR();
        if (more) stageu(t + 1, 1);
        lda(buf, 0, 1, a);
        mm(a, b, 1);
        SBAR();
        if (more) { stageu(t + 1, 2); VMC(6); } else { VMC(0); }
        lda(buf, 1, 0, a); ldb(buf, 1, b);
        mm(a, b, 0);
        SBAR();
        if (more) stageu(t + 1, 3);
        lda(buf, 1, 1, a);
        mm(a, b, 1);
        SBAR();
    }

    const int crow0 = m0 + wrow * 128 + ((lane >> 4) << 2);
    const int ccol  = n0 + wcol * 64 + (lane & 15);
    #pragma unroll
    for (int mi = 0; mi < 8; ++mi)
        #pragma unroll
        for (int fn = 0; fn < 4; ++fn)
            #pragma unroll
            for (int r = 0; r < 4; ++r)
                Cout[(size_t)(crow0 + mi * 16 + r) * N + ccol + fn * 16] =
                    f2h(acc[mi][fn][r]);
}

// ---------------------------------------------------------------------------
// 8-phase fused causal-conv + gate (same sync skeleton as gemm8):
//   H = bf16( tanh(conv(yb,Wf)) * sigmoid(conv(yb,Wg)) )
// Tile 256M x 128N, 512 thr = 8 waves (2M x 4N), per-wave out 128x32 per gate
// (accF[8][2] + accG[8][2] = 128 VGPR). K-loop = 2 taps x 16 K-tiles (BK=64).
// Phases: (kh0,F)(kh0,G)(kh1,F)(kh1,G), 16 MFMA each; A-frags reused F->G.
// Units/tile: A-kh0(16K), BFG-kh0(16K: BF8K+BG8K), A-kh1, BFG-kh1; one per
// phase, 2 gl_lds16/thread -> identical vmcnt ledger to gemm8 (6 at P1/P3).
// Tap-0 causal shift: staging clamps; LDS row 0 of A units zeroed (block-
// uniform branch, lgkmcnt+barrier) for blocks at sequence starts.
// ---------------------------------------------------------------------------
__global__ __launch_bounds__(512, 2)
void conv8(const u16* __restrict__ A, const u16* __restrict__ Wfgt,
           u16* __restrict__ H, int M)
{
    __shared__ u16 lds[2 * 32768];
    const int tid  = threadIdx.x;
    const int lane = tid & 63;
    const int wid  = tid >> 6;
    const int wrow = wid >> 2;        // 0..1
    const int wcol = wid & 3;         // 0..3
    const int gx = gridDim.x;         // 8
    const int lin = xcd_swz(blockIdx.x + gx * blockIdx.y, gx * gridDim.y);
    const int m0 = (lin / gx) * 256;
    const int n0 = (lin % gx) * 128;
    const int NT = 32;                // 2 taps x 16 K-tiles

    f32x4 accF[8][2] = {};
    f32x4 accG[8][2] = {};

    auto stageA = [&](int t, int kh) {
        u16* ubase = &lds[(t & 1) * 32768 + kh * 8192];
        const int tap = t >> 4;
        const int k0 = (t & 15) * 64 + kh * 32;
        const int sh = (tap == 0) ? 1 : 0;
        #pragma unroll
        for (int j = 0; j < 2; ++j) {
            const int c = wid + 8 * j;            // 0..15
            const int p = c * 64 + lane;          // 0..1023
            const int row = p >> 2;               // 0..255
            const int sp  = (p & 3) ^ ((row >> 1) & 3);
            int grow = m0 + row - sh;
            if (grow < 0) grow = 0;
            gl_lds16(A + (size_t)grow * C_DIM + k0 + sp * 8, ubase + c * 512);
        }
    };
    auto stageB = [&](int t, int kh) {
        u16* ubase = &lds[(t & 1) * 32768 + 16384 + kh * 8192];
        const int tap = t >> 4;
        const int k0 = (t & 15) * 64 + kh * 32;
        const u16* BF = Wfgt + (size_t)tap * 2 * C_DIM * C_DIM;
        const u16* BG = BF + (size_t)C_DIM * C_DIM;
        #pragma unroll
        for (int j = 0; j < 2; ++j) {
            const int c = wid + 8 * j;            // 0..15
            const int isG = c >> 3;
            const int p = (c & 7) * 64 + lane;    // 0..511
            const int row = p >> 2;               // 0..127
            const int sp  = (p & 3) ^ ((row >> 1) & 3);
            const u16* src = (isG ? BG : BF) + (size_t)(n0 + row) * C_DIM + k0 + sp * 8;
            gl_lds16(src, ubase + isG * 4096 + (c & 7) * 512);
        }
    };

    auto lda8 = [&](int buf, int kh, bf16x8 (&a)[8]) {
        const u16* base = &lds[buf * 32768 + kh * 8192];
        #pragma unroll
        for (int f = 0; f < 8; ++f) {
            const int row = wrow * 128 + f * 16 + (lane & 15);
            const int sp  = (lane >> 4) ^ ((row >> 1) & 3);
            a[f] = *(const bf16x8*)&base[row * 32 + sp * 8];
        }
    };
    auto ldb2 = [&](int buf, int kh, int isG, bf16x8 (&b)[2]) {
        const u16* base = &lds[buf * 32768 + 16384 + kh * 8192 + isG * 4096];
        #pragma unroll
        for (int f = 0; f < 2; ++f) {
            const int row = wcol * 32 + f * 16 + (lane & 15);
            const int sp  = (lane >> 4) ^ ((row >> 1) & 3);
            b[f] = *(const bf16x8*)&base[row * 32 + sp * 8];
        }
    };
    auto mm2 = [&](const bf16x8 (&a)[8], const bf16x8 (&b)[2], f32x4 (&acc)[8][2]) {
        __builtin_amdgcn_s_setprio(1);
        #pragma unroll
        for (int fm = 0; fm < 8; ++fm)
            #pragma unroll
            for (int fn = 0; fn < 2; ++fn)
                acc[fm][fn] = __builtin_amdgcn_mfma_f32_16x16x32_bf16(
                    a[fm], b[fn], acc[fm][fn], 0, 0, 0);
        __builtin_amdgcn_s_setprio(0);
    };

    const bool zrow = (m0 % T_SEQ) == 0;   // block-uniform

    auto zeroA = [&](int buf, int kh) {    // zero row 0 (32 u16) of A unit
        if (tid < 4) {
            u16x8 zz = {0,0,0,0,0,0,0,0};
            *(u16x8*)&lds[buf * 32768 + kh * 8192 + tid * 8] = zz;
        }
        asm volatile("s_waitcnt lgkmcnt(0)" ::: "memory");
        __builtin_amdgcn_sched_barrier(0);
        __builtin_amdgcn_s_barrier();
        __builtin_amdgcn_sched_barrier(0);
    };

    stageA(0, 0); stageB(0, 0); stageA(0, 1); stageB(0, 1);
    VMC(4);
    SBAR();

    bf16x8 a[8], bF[2], bG[2];
    for (int t = 0; t < NT; ++t) {
        const int buf = t & 1;
        const bool more = (t + 1 < NT);
        const bool z0 = zrow && (t < 16);   // tap-0 pass only
        // P1: (kh0, F); stage A-kh0(t+1)
        if (more) { stageA(t + 1, 0); VMC(6); } else { VMC(4); }
        if (z0) zeroA(buf, 0);
        lda8(buf, 0, a); ldb2(buf, 0, 0, bF);
        mm2(a, bF, accF);
        SBAR();
        // P2: (kh0, G); stage BFG-kh0(t+1); a reused
        if (more) stageB(t + 1, 0);
        ldb2(buf, 0, 1, bG);
        mm2(a, bG, accG);
        SBAR();
        // P3: (kh1, F); stage A-kh1(t+1)
        if (more) { stageA(t + 1, 1); VMC(6); } else { VMC(0); }
        if (z0) zeroA(buf, 1);
        lda8(buf, 1, a); ldb2(buf, 1, 0, bF);
        mm2(a, bF, accF);
        SBAR();
        // P4: (kh1, G); stage BFG-kh1(t+1); a reused
        if (more) stageB(t + 1, 1);
        ldb2(buf, 1, 1, bG);
        mm2(a, bG, accG);
        SBAR();
    }

    const int crow0 = m0 + wrow * 128 + ((lane >> 4) << 2);
    const int ccol  = n0 + wcol * 32 + (lane & 15);
    #pragma unroll
    for (int fm = 0; fm < 8; ++fm)
        #pragma unroll
        for (int fn = 0; fn < 2; ++fn)
            #pragma unroll
            for (int r = 0; r < 4; ++r) {
                const float fv = accF[fm][fn][r];
                const float gv = accG[fm][fn][r];
                const float th = 1.0f - 2.0f / (expf(2.0f * fv) + 1.0f);
                const float sg = 1.0f / (1.0f + expf(-gv));
                H[(size_t)(crow0 + fm * 16 + r) * C_DIM + ccol + fn * 16] = f2bf(th * sg);
            }
}

// ---------------------------------------------------------------------------
// Dual GEMM + product epilogue:
//   out = (A1 @ B1^T) * (A2 @ B2^T)   elementwise, f32 out
// ---------------------------------------------------------------------------
__global__ __launch_bounds__(256)
void dual_gemm(const u16* __restrict__ A1, const u16* __restrict__ B1, int K1,
               const u16* __restrict__ A2, const u16* __restrict__ B2, int K2,
               float* __restrict__ out, int M, int N)
{
    __shared__ u16 lds[2 * 2 * 4096];
    const int tid  = threadIdx.x;
    const int lane = tid & 63;
    const int wid  = tid >> 6;
    const int wr = wid >> 1, wc = wid & 1;
    const int gx = gridDim.x;
    const int lin = xcd_swz(blockIdx.x + gx * blockIdx.y, gx * gridDim.y);
    const int m0 = (lin / gx) * BM;
    const int n0 = (lin % gx) * BN;

    f32x4 acc1[4][4] = {};
    f32x4 acc2[4][4] = {};

    auto stage = [&](const u16* Ap, const u16* Bp, int K, int it, int buf) {
        const int k0 = it * BK;
        u16* base = &lds[buf * 8192];
        #pragma unroll
        for (int i = 0; i < 2; ++i) {
            const int chunk = wid + 4 * i;
            const int rloc  = chunk * 16 + (lane >> 2);
            const int slot  = (lane & 3) ^ ((rloc >> 1) & 3);
            gl_lds16(Bp + (size_t)(n0 + rloc) * K + k0 + slot * 8,
                     base + 4096 + chunk * 512);
            gl_lds16(Ap + (size_t)(m0 + rloc) * K + k0 + slot * 8,
                     base + chunk * 512);
        }
    };

    auto compute = [&](int buf, f32x4 (&acc)[4][4]) {
        const u16* base = &lds[buf * 8192];
        bf16x8 a[4], b[4];
        #pragma unroll
        for (int f = 0; f < 4; ++f) {
            const int row = wr * 64 + f * 16 + (lane & 15);
            const int sp  = ((lane >> 4) & 3) ^ ((row >> 1) & 3);
            a[f] = *(const bf16x8*)&base[row * 32 + sp * 8];
            const int rowb = wc * 64 + f * 16 + (lane & 15);
            const int spb  = ((lane >> 4) & 3) ^ ((rowb >> 1) & 3);
            b[f] = *(const bf16x8*)&base[4096 + rowb * 32 + spb * 8];
        }
        #pragma unroll
        for (int fm = 0; fm < 4; ++fm)
            #pragma unroll
            for (int fn = 0; fn < 4; ++fn)
                acc[fm][fn] = __builtin_amdgcn_mfma_f32_16x16x32_bf16(a[fm], b[fn], acc[fm][fn], 0, 0, 0);
    };

    const int NT1 = K1 / BK, NT2 = K2 / BK;
    stage(A1, B1, K1, 0, 0);
    int cur = 0;
    for (int it = 0; it < NT1; ++it) {
        __syncthreads();
        if (it + 1 < NT1) stage(A1, B1, K1, it + 1, cur ^ 1);
        else              stage(A2, B2, K2, 0, cur ^ 1);   // cross-phase prefetch
        compute(cur, acc1);
        cur ^= 1;
    }
    for (int it = 0; it < NT2; ++it) {
        __syncthreads();
        if (it + 1 < NT2) stage(A2, B2, K2, it + 1, cur ^ 1);
        compute(cur, acc2);
        cur ^= 1;
    }

    const int crow0 = m0 + wr * 64 + ((lane >> 4) << 2);
    const int ccol  = n0 + wc * 64 + (lane & 15);
    #pragma unroll
    for (int fm = 0; fm < 4; ++fm)
        #pragma unroll
        for (int fn = 0; fn < 4; ++fn)
            #pragma unroll
            for (int r = 0; r < 4; ++r) {
                const size_t idx = (size_t)(crow0 + fm * 16 + r) * N + ccol + fn * 16;
                out[idx] = acc1[fm][fn][r] * acc2[fm][fn][r];
            }
}

// ---------------------------------------------------------------------------
// Segmented parallel scan, 3-pass STREAMING (no register arrays -> no spill),
// 128B-coalesced kq access.
// ---------------------------------------------------------------------------
#define SSEG 32
#define SCHB 32
#define SSL (T_SEQ / SSEG)   // 64

__global__ __launch_bounds__(1024, 1)
void scan_kernel(u16* __restrict__ kq, u16* __restrict__ xyb)
{
    __shared__ float  lmax[SSEG][SCHB];
    __shared__ float2 lprod[SSEG][SCHB];
    const int blk = blockIdx.x;
    const int b   = blk >> 5;
    const int c0  = (blk & 31) * SCHB;
    const int ch  = threadIdx.x & (SCHB - 1);
    const int seg = threadIdx.x >> 5;
    const int c   = c0 + ch;
    const int t0  = seg * SSL;
    const size_t baseh = (size_t)b * T_SEQ * 2048 + 2 * c + (size_t)t0 * 2048;
    const size_t base1 = (size_t)b * T_SEQ * C_DIM + c + (size_t)t0 * C_DIM;

    float m2 = 0.f;
    {
        size_t idx = baseh;
        for (int t = 0; t < SSL; ++t) {
            const u32 v = *(const u32*)&kq[idx];
            const float re = h2f((u16)(v & 0xffffu));
            const float im = h2f((u16)(v >> 16));
            m2 = fmaxf(m2, re * re + im * im);
            idx += 2048;
        }
    }
    lmax[seg][ch] = sqrtf(m2);
    __syncthreads();
    #pragma unroll
    for (int s = 1; s < SSEG; s <<= 1) {
        const float v = lmax[seg][ch];
        const float u = (seg >= s) ? lmax[seg - s][ch] : 0.f;
        __syncthreads();
        lmax[seg][ch] = fmaxf(v, u);
        __syncthreads();
    }
    const float premax = (seg > 0) ? lmax[seg - 1][ch] : 0.f;

    float pr = 1.f, pi = 0.f;
    float m = premax;
    {
        size_t idx = baseh, idx1 = base1;
        for (int t = 0; t < SSL; ++t) {
            const u32 v = *(const u32*)&kq[idx];
            const float re = h2f((u16)(v & 0xffffu));
            const float im = h2f((u16)(v >> 16));
            m = fmaxf(m, sqrtf(re * re + im * im));
            const float inv = 1.f / m;
            const float r0 = re * inv, r1 = im * inv;
            const float nr = pr * r0 - pi * r1;
            const float ni = pr * r1 + pi * r0;
            pr = nr; pi = ni;
            const float xv = h2f(xyb[idx1]);
            xyb[idx1] = f2bf(xv * m);
            idx += 2048; idx1 += C_DIM;
        }
    }
    lprod[seg][ch] = make_float2(pr, pi);
    __syncthreads();
    #pragma unroll
    for (int s = 1; s < SSEG; s <<= 1) {
        const float2 v = lprod[seg][ch];
        const float2 u = (seg >= s) ? lprod[seg - s][ch] : make_float2(1.f, 0.f);
        __syncthreads();
        lprod[seg][ch] = make_float2(u.x * v.x - u.y * v.y,
                                     u.x * v.y + u.y * v.x);
        __syncthreads();
    }
    float ppr = 1.f, ppi = 0.f;
    if (seg > 0) { const float2 pp = lprod[seg - 1][ch]; ppr = pp.x; ppi = pp.y; }

    pr = 1.f; pi = 0.f;
    m = premax;
    {
        size_t idx = baseh;
        for (int t = 0; t < SSL; ++t) {
            const u32 v = *(const u32*)&kq[idx];
            const float re = h2f((u16)(v & 0xffffu));
            const float im = h2f((u16)(v >> 16));
            m = fmaxf(m, sqrtf(re * re + im * im));
            const float inv = 1.f / m;
            const float r0 = re * inv, r1 = im * inv;
            const float nr = pr * r0 - pi * r1;
            const float ni = pr * r1 + pi * r0;
            pr = nr; pi = ni;
            const float fr = ppr * nr - ppi * ni;
            const float fi = ppr * ni + ppi * nr;
            *(u32*)&kq[idx] = ((u32)f2bf(fi) << 16) | (u32)f2bf(fr);
            idx += 2048;
        }
    }
}

// ---------------------------------------------------------------------------
// Prep kernels
// ---------------------------------------------------------------------------
__global__ void cvt_weights(const float* __restrict__ Wk, const float* __restrict__ Wa,
                            const float* __restrict__ Wo, u16* __restrict__ Wkh,
                            u16* __restrict__ Wab, u16* __restrict__ Wob)
{
    const int n1 = 2048 * 1024, n2 = 2 * 2048 * 1024, n3 = n2 + 1024 * 1024;
    const int i = (blockIdx.x * blockDim.x + threadIdx.x) * 4;
    if (i < n1) {
        const float4 v = *(const float4*)&Wk[i];
        ushort4 o; o.x = f2h(v.x); o.y = f2h(v.y); o.z = f2h(v.z); o.w = f2h(v.w);
        *(ushort4*)&Wkh[i] = o;
    } else if (i < n2) {
        const int j = i - n1;
        const float4 v = *(const float4*)&Wa[j];
        ushort4 o; o.x = f2bf(v.x); o.y = f2bf(v.y); o.z = f2bf(v.z); o.w = f2bf(v.w);
        *(ushort4*)&Wab[j] = o;
    } else if (i < n3) {
        const int j = i - n2;
        const float4 v = *(const float4*)&Wo[j];
        ushort4 o; o.x = f2bf(v.x); o.y = f2bf(v.y); o.z = f2bf(v.z); o.w = f2bf(v.w);
        *(ushort4*)&Wob[j] = o;
    }
}

__global__ void cvt_f16(const float* __restrict__ src, u16* __restrict__ dst, int n)
{
    const int i = (blockIdx.x * blockDim.x + threadIdx.x) * 4;
    if (i >= n) return;
    const float4 v = *(const float4*)&src[i];
    ushort4 o;
    o.x = f2h(v.x); o.y = f2h(v.y); o.z = f2h(v.z); o.w = f2h(v.w);
    *(ushort4*)&dst[i] = o;
}

// Wf/Wg [2,K,N] (tap,k,n) -> Wfgt [tap][F/G][n][k] bf16
__global__ __launch_bounds__(256)
void wtrans(const float* __restrict__ Wf, const float* __restrict__ Wg,
            u16* __restrict__ dst)
{
    __shared__ float tile[64][65];
    const int z = blockIdx.z;
    const float* src = ((z < 2) ? Wf : Wg) + (size_t)(z & 1) * C_DIM * C_DIM;
    u16* d = dst + (size_t)(z & 1) * (2 * C_DIM) * C_DIM
                 + ((z < 2) ? (size_t)0 : (size_t)C_DIM * C_DIM);
    const int k0 = blockIdx.x * 64;
    const int n0 = blockIdx.y * 64;
    const int tx = threadIdx.x & 63, ty = threadIdx.x >> 6;
    #pragma unroll
    for (int i = 0; i < 16; ++i) {
        const int r = ty + i * 4;
        tile[r][tx] = src[(size_t)(k0 + r) * C_DIM + n0 + tx];
    }
    __syncthreads();
    #pragma unroll
    for (int i = 0; i < 16; ++i) {
        const int r = ty + i * 4;
        d[(size_t)(n0 + r) * C_DIM + k0 + tx] = f2bf(tile[tx][r]);
    }
}

// ---------------------------------------------------------------------------
// ws layout (bytes):
//   0         : kq  u16 [16384,2048]  67.1MB  (kh fp16 -> kv bf16 in-place)
//   67108864  : yb  u16 [16384,1024]  33.6MB  (xh fp16 -> yb bf16 in-place)
//   100663296 : hb  u16 [16384,1024]  33.6MB
//   134217728 : Wkh(f16) 4.2 | Wab 4.2 | Wfgt 8.4 | Wob 2.1   (~153MB total)
// ---------------------------------------------------------------------------
extern "C" void kernel_launch(void* const* d_in, const int* in_sizes, int n_in,
                              void* d_out, int out_size, void* d_ws, size_t ws_size,
                              hipStream_t stream)
{
    const float* x  = (const float*)d_in[0];
    const float* Wk = (const float*)d_in[1];
    const float* Wa = (const float*)d_in[2];
    const float* Wf = (const float*)d_in[3];
    const float* Wg = (const float*)d_in[4];
    const float* Wo = (const float*)d_in[5];
    float* out = (float*)d_out;

    const int M = 8 * T_SEQ;
    u16* kq   = (u16*)d_ws;
    u16* yb   = (u16*)((char*)d_ws + 67108864ull);   // xh first, then yb
    u16* hb   = (u16*)((char*)d_ws + 100663296ull);
    u16* Wkh  = (u16*)((char*)d_ws + 134217728ull);
    u16* Wab  = Wkh + 2048 * 1024;
    u16* Wfgt = Wab + 2048 * 1024;
    u16* Wob  = Wfgt + 2ull * 2048 * 1024;

    cvt_weights<<<(5 * 1024 * 1024 / 4 + 255) / 256, 256, 0, stream>>>(
        Wk, Wa, Wo, Wkh, Wab, Wob);
    wtrans  <<<dim3(16, 16, 4), 256, 0, stream>>>(Wf, Wg, Wfgt);
    cvt_f16 <<<(M * 1024 / 4) / 256, 256, 0, stream>>>(x, yb, M * 1024);  // xh

    // 1) kq = fp16( x @ Wk^T )  (8-phase 256^2 fp16 MFMA)
    gemm8<<<dim3(2048 / 256, M / 256), 512, 0, stream>>>(
        yb, Wkh, kq, M, 2048, 1024);

    // 2) streaming scan: kv bf16 in-place; yb = bf16(xh*scale) in-place
    scan_kernel<<<256, 1024, 0, stream>>>(kq, yb);

    // 3) hb = bf16(tanh(conv(yb,Wf)) * sigmoid(conv(yb,Wg)))  (8-phase)
    conv8<<<dim3(1024 / 128, M / 256), 512, 0, stream>>>(yb, Wfgt, hb, M);

    // 4) out = (kv @ Wa^T) * (hb @ Wo^T)   (dual GEMM, product epilogue)
    dual_gemm<<<dim3(1024 / BN, M / BM), 256, 0, stream>>>(
        kq, Wab, 2048, hb, Wob, 1024, out, M, 1024);
}